// Round 10
// baseline (334.974 us; speedup 1.0000x reference)
//
#include <hip/hip_runtime.h>
#include <math.h>

#define BN_ 2
#define NN 1024
#define DDIM 256
#define HH 8
#define HDIM 32
#define FFD 1024
#define EPSV 1e-5f
#define SCALEV 0.17677669529663687f
#define LPAD 72

typedef __attribute__((ext_vector_type(8))) short s16x8;
typedef __attribute__((ext_vector_type(4))) float f32x4;

__device__ __forceinline__ float gelu_f(float x){
  return 0.5f*x*(1.0f+erff(x*0.70710678118654752f));
}
__device__ __forceinline__ unsigned int pack_bf16(float lo, float hi){
  unsigned int ul = __float_as_uint(lo), uh = __float_as_uint(hi);
  ul += 0x7fff + ((ul>>16)&1);
  uh += 0x7fff + ((uh>>16)&1);
  return (ul>>16) | (uh & 0xffff0000u);
}
__device__ __forceinline__ unsigned short f2bf(float x){
  unsigned int u = __float_as_uint(x);
  u += 0x7fff + ((u>>16)&1);
  return (unsigned short)(u>>16);
}
__device__ __forceinline__ float bf2f(unsigned short u){
  return __uint_as_float(((unsigned int)u)<<16);
}
// truncation-pack two f32 -> one dword of 2 bf16 (v_perm_b32)
__device__ __forceinline__ unsigned int packtr(float lo, float hi){
  return __builtin_amdgcn_perm(__float_as_uint(hi), __float_as_uint(lo), 0x07060302u);
}
__device__ __forceinline__ f32x4 mfma16(s16x8 a, s16x8 b, f32x4 c){
  return __builtin_amdgcn_mfma_f32_16x16x32_bf16(a,b,c,0,0,0);
}

// ---------------- LayerNorm: f32 in, bf16 out --------------------------------
__global__ __launch_bounds__(256) void ln_kernel(const float* __restrict__ x,
    const float* __restrict__ g, const float* __restrict__ b,
    unsigned short* __restrict__ out){
  int row = blockIdx.x, tid = threadIdx.x;
  float val = x[(size_t)row*DDIM + tid];
  float s = val;
  #pragma unroll
  for (int o=32;o;o>>=1) s += __shfl_xor(s,o);
  __shared__ float sb[4], sb2[4];
  if ((tid&63)==0) sb[tid>>6]=s;
  __syncthreads();
  float mean = (sb[0]+sb[1]+sb[2]+sb[3]) * (1.0f/DDIM);
  float d = val-mean;
  float vs = d*d;
  #pragma unroll
  for (int o=32;o;o>>=1) vs += __shfl_xor(vs,o);
  if ((tid&63)==0) sb2[tid>>6]=vs;
  __syncthreads();
  float var = (sb2[0]+sb2[1]+sb2[2]+sb2[3]) * (1.0f/DDIM);
  out[(size_t)row*DDIM + tid] = f2bf(d*rsqrtf(var+EPSV)*g[tid]+b[tid]);
}

// ---------------- RoPE tables -------------------------------------------------
__global__ __launch_bounds__(256) void rope_table(float* __restrict__ sint, float* __restrict__ cost){
  int idx = blockIdx.x*256+threadIdx.x;   // 16384
  int i = idx >> 4, d = idx & 15;
  float freq = (float)i * powf(10000.0f, -(float)d/16.0f);
  sint[idx]=sinf(freq); cost[idx]=cosf(freq);
}

// ---------------- weight convert+transpose f32(K,NC) -> bf16 WT(NC,K) --------
__global__ __launch_bounds__(256) void wt_convert(const float* __restrict__ in,
    unsigned short* __restrict__ out, int K, int NC, int scaleCols, float scaleVal){
  __shared__ float tile[32][33];
  int tn0 = blockIdx.x*32;
  int tk0 = blockIdx.y*32;
  size_t loff = (size_t)blockIdx.z * K * NC;
  int t = threadIdx.x;
  int col = t & 31, rr = t >> 5;
  #pragma unroll
  for (int i=0;i<4;++i){
    int row = rr + i*8;
    tile[row][col] = in[loff + (size_t)(tk0+row)*NC + tn0+col];
  }
  __syncthreads();
  #pragma unroll
  for (int i=0;i<4;++i){
    int row = rr + i*8;
    int n = tn0 + row;
    float s = (n < scaleCols) ? scaleVal : 1.0f;
    out[loff + (size_t)n*K + tk0 + col] = f2bf(tile[col][row]*s);
  }
}

// ------------- split qkv + rope (bf16 in/out) --------------------------------
__global__ __launch_bounds__(256) void rope_apply_bf(const unsigned short* __restrict__ qkv,
    const float* __restrict__ sint, const float* __restrict__ cost,
    unsigned short* __restrict__ q, unsigned short* __restrict__ k,
    unsigned short* __restrict__ v){
  int row = blockIdx.x;                 // b*1024 + i
  int b = row>>10, i = row&1023;
  int tid = threadIdx.x; int h = tid>>5, d = tid&31;
  const unsigned short* base = qkv + (size_t)row*768;
  size_t oidx = (((size_t)((b<<3)+h)<<10) + i)*32 + d;
  v[oidx] = base[512 + h*32 + d];
  int dd = (d<16) ? d : d-16;
  float s = sint[i*16+dd], c = cost[i*16+dd];
  float q1 = bf2f(base[h*32+dd]), q2 = bf2f(base[h*32+dd+16]);
  q[oidx] = f2bf((d<16) ? (q1*c - q2*s) : (q2*c + q1*s));
  float k1 = bf2f(base[256+h*32+dd]), k2 = bf2f(base[256+h*32+dd+16]);
  k[oidx] = f2bf((d<16) ? (k1*c - k2*s) : (k2*c + k1*s));
}

// ------------- rel precompute: per-node separable parts + W2T ----------------
// blocks 0..511: A[node][64] (=b1+bv), A2[node][64] (=bv). block 512: W2T[16][64]
__global__ __launch_bounds__(256) void rel_pre(const float* __restrict__ coords,
    const float* __restrict__ vel, const float* __restrict__ W1,
    const float* __restrict__ b1, const float* __restrict__ W2,
    float* __restrict__ A, float* __restrict__ A2, unsigned short* __restrict__ W2T){
  if (blockIdx.x == 512){
    int t = threadIdx.x;
    #pragma unroll
    for (int e=0;e<4;++e){
      int idx = t*4+e;              // n*64 + k
      int n = idx>>6, kk = idx&63;
      W2T[idx] = (n<8) ? f2bf(W2[kk*8+n]) : 0;
    }
    return;
  }
  int gid = blockIdx.x*256 + threadIdx.x;  // 2048*64
  int node = gid >> 6, r = gid & 63;
  float c0 = coords[node*2], c1 = coords[node*2+1];
  float v0 = vel[node*2],    v1 = vel[node*2+1];
  float bv = c0*W1[r] + c1*W1[64+r] + v0*W1[192+r] + v1*W1[256+r];
  A[gid] = b1[r] + bv;
  A2[gid] = bv;
}

// ------------- rel fused v5: A-frag layout, reg-resident, SW-pipelined -------
// Block = (b,i); 4 waves; wave w covers j in [w*256,+256) as 16 subtiles of 16.
// Lane l: j = j0+(l&15), r in {lg*8..+7, 32+lg*8..+7}. No LDS, no barriers.
// launch_bounds(256,4): ~128 VGPR cap so Ai/Wd/W2-frags stay register-resident.
__global__ __launch_bounds__(256, 4) void rel_fused5(const float* __restrict__ coords,
    const float* __restrict__ A, const float* __restrict__ A2,
    const float* __restrict__ W1, const unsigned short* __restrict__ W2T,
    const float* __restrict__ b2, unsigned short* __restrict__ relbf){
  const int tid = threadIdx.x;
  const int nodei = blockIdx.x;
  const int b = nodei >> 10, i = nodei & 1023;
  const int w = tid>>6, l = tid&63, lc = l&15, lg = l>>4;
  float ci0 = coords[nodei*2], ci1 = coords[nodei*2+1];

  // per-lane r-slice invariants (kept in VGPRs across the whole j loop)
  const float* Ap = A + (size_t)nodei*64 + lg*8;
  const float4 aA = *(const float4*)(Ap);
  const float4 aB = *(const float4*)(Ap+4);
  const float4 aC = *(const float4*)(Ap+32);
  const float4 aD = *(const float4*)(Ap+36);
  const float* Wp = W1 + 128 + lg*8;
  const float4 wA = *(const float4*)(Wp);
  const float4 wB = *(const float4*)(Wp+4);
  const float4 wC = *(const float4*)(Wp+32);
  const float4 wD = *(const float4*)(Wp+36);

  // B-fragment of W2 (n=lc -> h, k=lg*8+e -> r)
  const s16x8 bf0 = *(const s16x8*)&W2T[lc*64 + lg*8];
  const s16x8 bf1 = *(const s16x8*)&W2T[lc*64 + 32 + lg*8];
  const float b2v = (lc<8) ? b2[lc] : 0.f;

  // running pointers: subtile st -> +32 floats coords, +1024 floats A2
  const float* cb = coords + (size_t)((b<<10) + w*256 + lc)*2;
  const float* ab = A2 + (size_t)((b<<10) + w*256 + lc)*64 + lg*8;
  unsigned short* ob = relbf + ((size_t)b<<23) + ((size_t)i<<10)
                     + ((size_t)(lc&7)<<20) + (unsigned)(w*256 + lg*4);

  // prefetch subtile 0
  float2 cj = *(const float2*)cb;
  float4 q0 = *(const float4*)(ab);
  float4 q1 = *(const float4*)(ab+4);
  float4 q2 = *(const float4*)(ab+32);
  float4 q3 = *(const float4*)(ab+36);

  #pragma unroll
  for (int st=0; st<16; ++st){
    // issue next subtile's loads (hide L2 latency under gelu block)
    float2 cjn; float4 n0,n1,n2,n3;
    if (st < 15){
      const float* cn = cb + (st+1)*32;
      const float* an = ab + (st+1)*1024;
      cjn = *(const float2*)cn;
      n0 = *(const float4*)(an);
      n1 = *(const float4*)(an+4);
      n2 = *(const float4*)(an+32);
      n3 = *(const float4*)(an+36);
    }
    float dx = ci0-cj.x, dy = ci1-cj.y;
    float d = sqrtf(fmaf(dx,dx,dy*dy));
    float gg[16];
    {
      float av[16] = {aA.x,aA.y,aA.z,aA.w, aB.x,aB.y,aB.z,aB.w,
                      aC.x,aC.y,aC.z,aC.w, aD.x,aD.y,aD.z,aD.w};
      float wv[16] = {wA.x,wA.y,wA.z,wA.w, wB.x,wB.y,wB.z,wB.w,
                      wC.x,wC.y,wC.z,wC.w, wD.x,wD.y,wD.z,wD.w};
      float tv[16] = {q0.x,q0.y,q0.z,q0.w, q1.x,q1.y,q1.z,q1.w,
                      q2.x,q2.y,q2.z,q2.w, q3.x,q3.y,q3.z,q3.w};
      #pragma unroll
      for (int e=0; e<16; ++e){
        float t = fmaf(d, wv[e], av[e] - tv[e]);
        float u = t*t;
        float p = fmaf(u, 0.0099735570f, -0.0664904395f);
        p = fmaf(u, p, 0.3989422804f);
        gg[e] = fmaf(u, p, 0.5f*t);
      }
    }
    union { unsigned int u[4]; s16x8 v; } p0, p1;
    p0.u[0]=packtr(gg[0],gg[1]);  p0.u[1]=packtr(gg[2],gg[3]);
    p0.u[2]=packtr(gg[4],gg[5]);  p0.u[3]=packtr(gg[6],gg[7]);
    p1.u[0]=packtr(gg[8],gg[9]);  p1.u[1]=packtr(gg[10],gg[11]);
    p1.u[2]=packtr(gg[12],gg[13]);p1.u[3]=packtr(gg[14],gg[15]);
    f32x4 z; z[0]=0.f; z[1]=0.f; z[2]=0.f; z[3]=0.f;
    z = mfma16(p0.v, bf0, z);
    z = mfma16(p1.v, bf1, z);
    if (lc < 8){
      unsigned int o0 = pack_bf16(z[0]+b2v, z[1]+b2v);
      unsigned int o1 = pack_bf16(z[2]+b2v, z[3]+b2v);
      unsigned short* op = ob + st*16;
      *(unsigned int*)op     = o0;
      *(unsigned int*)(op+2) = o1;
    }
    cj = cjn; q0 = n0; q1 = n1; q2 = n2; q3 = n3;
  }
}

// ------------- MFMA flash attention (all-bf16 inputs) -------------------------
__global__ __launch_bounds__(256) void attn_mfma(
    const unsigned short* __restrict__ q, const unsigned short* __restrict__ kk,
    const unsigned short* __restrict__ vv, const unsigned short* __restrict__ relbf,
    unsigned short* __restrict__ out){
  int bh = blockIdx.x >> 5;
  int i0 = (blockIdx.x & 31) * 32;
  int tid = threadIdx.x;
  int w  = tid >> 6;
  int l  = tid & 63;
  int lc = l & 15;
  int lg = l >> 4;

  __shared__ __align__(16) unsigned short VT[2][32*LPAD];
  __shared__ __align__(16) unsigned short PL[2][32*LPAD];
  __shared__ __align__(16) float wmaxs[2][32][4];
  __shared__ __align__(16) float wsums[2][32][4];
  __shared__ float mld[2][32];
  __shared__ float lld[2][32];

  const unsigned short* qb = q + ((size_t)(bh<<10) + i0)*32;
  const unsigned short* kb = kk + ((size_t)bh<<15);
  const unsigned short* vb = vv + ((size_t)bh<<15);
  const unsigned short* relb = relbf + ((size_t)bh<<20) + ((size_t)i0<<10);

  s16x8 qf0 = *(const s16x8*)(qb + (size_t)lc*32 + lg*8);
  s16x8 qf1 = *(const s16x8*)(qb + (size_t)(16+lc)*32 + lg*8);

  if (tid < 32){ mld[0][tid] = -1e30f; lld[0][tid] = 0.f; }

  f32x4 acc; acc[0]=0.f; acc[1]=0.f; acc[2]=0.f; acc[3]=0.f;
  const int dh  = w & 1;
  const int pih = w >> 1;

  for (int t=0; t<16; ++t){
    const int c = t & 1, nx = c ^ 1;
    const int j0 = t*64;
    {
      int jj = tid & 63, d0 = (tid >> 6)*8;
      s16x8 v8 = *(const s16x8*)(vb + (size_t)(j0+jj)*32 + d0);
      unsigned short* dst = VT[c];
      #pragma unroll
      for (int e=0;e<8;++e) dst[(d0+e)*LPAD + jj] = (unsigned short)v8[e];
    }
    s16x8 kf = *(const s16x8*)(kb + (size_t)(j0 + w*16 + lc)*32 + lg*8);
    f32x4 z; z[0]=0.f; z[1]=0.f; z[2]=0.f; z[3]=0.f;
    f32x4 s0 = mfma16(qf0, kf, z);
    f32x4 s1 = mfma16(qf1, kf, z);
    float sv0[4], sv1[4], rm0[4], rm1[4];
    const int jc = j0 + w*16 + lc;
    #pragma unroll
    for (int r=0;r<4;++r){
      int row0 = lg*4 + r;
      sv0[r] = s0[r] + bf2f(relb[(size_t)row0*1024 + jc]);
      sv1[r] = s1[r] + bf2f(relb[(size_t)(row0+16)*1024 + jc]);
      float a0 = sv0[r], a1 = sv1[r];
      #pragma unroll
      for (int o=1;o<16;o<<=1){
        a0 = fmaxf(a0, __shfl_xor(a0,o));
        a1 = fmaxf(a1, __shfl_xor(a1,o));
      }
      rm0[r]=a0; rm1[r]=a1;
    }
    if (lc == 0){
      #pragma unroll
      for (int r=0;r<4;++r){
        wmaxs[c][lg*4+r][w]    = rm0[r];
        wmaxs[c][lg*4+r+16][w] = rm1[r];
      }
    }
    __syncthreads();
    float mn0[4], mn1[4], sc0[4], sc1[4];
    #pragma unroll
    for (int r=0;r<4;++r){
      int row0 = lg*4+r;
      float4 wm0 = *(const float4*)wmaxs[c][row0];
      float4 wm1 = *(const float4*)wmaxs[c][row0+16];
      float mo0 = mld[c][row0], mo1 = mld[c][row0+16];
      float t0 = fmaxf(fmaxf(wm0.x,wm0.y), fmaxf(wm0.z,wm0.w));
      float t1 = fmaxf(fmaxf(wm1.x,wm1.y), fmaxf(wm1.z,wm1.w));
      mn0[r] = fmaxf(mo0, t0);  mn1[r] = fmaxf(mo1, t1);
      sc0[r] = __expf(mo0 - mn0[r]); sc1[r] = __expf(mo1 - mn1[r]);
    }
    float ps0[4], ps1[4];
    #pragma unroll
    for (int r=0;r<4;++r){
      int row0 = lg*4+r;
      float p0 = __expf(sv0[r]-mn0[r]);
      float p1 = __expf(sv1[r]-mn1[r]);
      PL[c][(size_t)row0*LPAD + w*16 + lc]      = f2bf(p0);
      PL[c][(size_t)(row0+16)*LPAD + w*16 + lc] = f2bf(p1);
      #pragma unroll
      for (int o=1;o<16;o<<=1){
        p0 += __shfl_xor(p0,o);
        p1 += __shfl_xor(p1,o);
      }
      ps0[r]=p0; ps1[r]=p1;
    }
    if (lc == 0){
      #pragma unroll
      for (int r=0;r<4;++r){
        wsums[c][lg*4+r][w]    = ps0[r];
        wsums[c][lg*4+r+16][w] = ps1[r];
      }
    }
    #pragma unroll
    for (int r=0;r<4;++r){
      float s = (pih==0) ? sc0[r] : sc1[r];
      acc[r] *= s;
    }
    __syncthreads();
    #pragma unroll
    for (int kc=0;kc<2;++kc){
      s16x8 pa = *(const s16x8*)&PL[c][(size_t)(pih*16 + lc)*LPAD + kc*32 + lg*8];
      s16x8 vf = *(const s16x8*)&VT[c][(size_t)(dh*16 + lc)*LPAD + kc*32 + lg*8];
      acc = mfma16(pa, vf, acc);
    }
    if (w==0 && lc==0){
      #pragma unroll
      for (int r=0;r<4;++r){
        int row0 = lg*4+r;
        float4 u0 = *(const float4*)wsums[c][row0];
        float4 u1 = *(const float4*)wsums[c][row0+16];
        lld[nx][row0]    = lld[c][row0]*sc0[r]    + (u0.x+u0.y+u0.z+u0.w);
        lld[nx][row0+16] = lld[c][row0+16]*sc1[r] + (u1.x+u1.y+u1.z+u1.w);
        mld[nx][row0]    = mn0[r];
        mld[nx][row0+16] = mn1[r];
      }
    }
  }
  __syncthreads();
  int b = bh>>3, hh = bh&7;
  #pragma unroll
  for (int r=0;r<4;++r){
    int row = pih*16 + lg*4 + r;
    float li = lld[0][row];
    out[((size_t)((b<<10)+i0+row))*256 + hh*32 + dh*16 + lc] = f2bf(acc[r]/li);
  }
}

// ------------- MFMA GEMM: C[M,NC] = A[M,K] @ W[K,NC], A bf16, WT bf16(NC,K) --
template<int K, int NC, int EPI, int BM, int BNt>
__global__ __launch_bounds__(256) void gemm_mfma(
    const unsigned short* __restrict__ Aa, const unsigned short* __restrict__ WT,
    const float* __restrict__ bias, const float* __restrict__ resid,
    void* __restrict__ outv){
  constexpr int WMm = BM/2, WNn = BNt/2;
  constexpr int FM = WMm/16, FN = WNn/16;
  constexpr int LP = 40;
  __shared__ __align__(16) unsigned short As[BM*LP];
  __shared__ __align__(16) unsigned short Bs[BNt*LP];
  const int tid = threadIdx.x;
  const int w = tid>>6, l = tid&63, lc = l&15, lg = l>>4;
  const int wm = w&1, wn = w>>1;
  const int n0 = blockIdx.x*BNt, m0 = blockIdx.y*BM;
  f32x4 acc[FM][FN];
  #pragma unroll
  for (int a=0;a<FM;++a)
    #pragma unroll
    for (int c=0;c<FN;++c){ acc[a][c][0]=0.f; acc[a][c][1]=0.f; acc[a][c][2]=0.f; acc[a][c][3]=0.f; }

  for (int k0=0; k0<K; k0+=32){
    __syncthreads();
    if constexpr (BM==64){
      int row = tid>>2, cg = tid&3;
      *(s16x8*)&As[row*LP+cg*8] = *(const s16x8*)&Aa[(size_t)(m0+row)*K + k0 + cg*8];
    } else {
      int row = tid>>3, cg = tid&7;
      *(ushort4*)&As[row*LP+cg*4] = *(const ushort4*)&Aa[(size_t)(m0+row)*K + k0 + cg*4];
    }
    if constexpr (BNt==64){
      int row = tid>>2, cg = tid&3;
      *(s16x8*)&Bs[row*LP+cg*8] = *(const s16x8*)&WT[(size_t)(n0+row)*K + k0 + cg*8];
    } else {
      int row = tid>>3, cg = tid&7;
      *(ushort4*)&Bs[row*LP+cg*4] = *(const ushort4*)&WT[(size_t)(n0+row)*K + k0 + cg*4];
    }
    __syncthreads();
    s16x8 af[FM], bv[FN];
    #pragma unroll
    for (int a=0;a<FM;++a) af[a] = *(const s16x8*)&As[(wm*WMm + a*16 + lc)*LP + lg*8];
    #pragma unroll
    for (int c=0;c<FN;++c) bv[c] = *(const s16x8*)&Bs[(wn*WNn + c*16 + lc)*LP + lg*8];
    #pragma unroll
    for (int a=0;a<FM;++a)
      #pragma unroll
      for (int c=0;c<FN;++c) acc[a][c] = mfma16(af[a], bv[c], acc[a][c]);
  }
  #pragma unroll
  for (int a=0;a<FM;++a){
    #pragma unroll
    for (int c=0;c<FN;++c){
      int n = n0 + wn*WNn + c*16 + lc;
      float bvv = (EPI!=0) ? bias[n] : 0.f;
      #pragma unroll
      for (int r=0;r<4;++r){
        int m = m0 + wm*WMm + a*16 + lg*4 + r;
        float vv = acc[a][c][r];
        if constexpr (EPI==0){
          ((unsigned short*)outv)[(size_t)m*NC + n] = f2bf(vv);
        } else if constexpr (EPI==1){
          ((float*)outv)[(size_t)m*NC + n] = vv + bvv + resid[(size_t)m*NC + n];
        } else {
          ((unsigned short*)outv)[(size_t)m*NC + n] = f2bf(gelu_f(vv + bvv));
        }
      }
    }
  }
}

extern "C" void kernel_launch(void* const* d_in, const int* in_sizes, int n_in,
                              void* d_out, int out_size, void* d_ws, size_t ws_size,
                              hipStream_t stream){
  const float* x_in  = (const float*)d_in[0];
  const float* coords= (const float*)d_in[1];
  const float* vel   = (const float*)d_in[2];
  const float* ln1_g = (const float*)d_in[3];
  const float* ln1_b = (const float*)d_in[4];
  const float* Wqkv  = (const float*)d_in[5];
  const float* relW1 = (const float*)d_in[6];
  const float* relb1 = (const float*)d_in[7];
  const float* relW2 = (const float*)d_in[8];
  const float* relb2 = (const float*)d_in[9];
  const float* Wout  = (const float*)d_in[10];
  const float* bout  = (const float*)d_in[11];
  const float* ln2_g = (const float*)d_in[12];
  const float* ln2_b = (const float*)d_in[13];
  const float* Wf1   = (const float*)d_in[14];
  const float* bf1   = (const float*)d_in[15];
  const float* Wf2   = (const float*)d_in[16];
  const float* bf2   = (const float*)d_in[17];

  float* x = (float*)d_out;
  unsigned short* us = (unsigned short*)d_ws;
  unsigned short* hbf   = us;                    // 524288
  unsigned short* qkvbf = hbf   + 524288;        // 1572864
  unsigned short* qbf   = qkvbf + 1572864;       // 524288
  unsigned short* kbf   = qbf   + 524288;        // 524288
  unsigned short* vbf   = kbf   + 524288;        // 524288
  unsigned short* attbf = vbf   + 524288;        // 524288
  unsigned short* midbf = attbf + 524288;        // 2097152
  unsigned short* relbf = midbf + 2097152;       // 16777216
  unsigned short* WqkvT = relbf + 16777216;      // 393216
  unsigned short* WoutT = WqkvT + 393216;        // 131072
  unsigned short* Wf1T  = WoutT + 131072;        // 524288
  unsigned short* Wf2T  = Wf1T  + 524288;        // 524288
  unsigned short* W2Tbf = Wf2T  + 524288;        // 1024
  float* Arel  = (float*)(W2Tbf + 1024);         // 131072
  float* A2rel = Arel + 131072;                  // 131072
  float* sint  = A2rel + 131072;                 // 16384
  float* cost  = sint + 16384;                   // 16384

  hipMemcpyAsync(x, x_in, sizeof(float)*524288, hipMemcpyDeviceToDevice, stream);
  rope_table<<<64,256,0,stream>>>(sint,cost);
  wt_convert<<<dim3(24,8,2),256,0,stream>>>(Wqkv, WqkvT, 256, 768, 256, SCALEV);
  wt_convert<<<dim3(8,8,2),256,0,stream>>>(Wout, WoutT, 256, 256, 0, 1.0f);
  wt_convert<<<dim3(32,8,2),256,0,stream>>>(Wf1, Wf1T, 256, 1024, 0, 1.0f);
  wt_convert<<<dim3(8,32,2),256,0,stream>>>(Wf2, Wf2T, 1024, 256, 0, 1.0f);

  for (int l=0;l<2;++l){
    ln_kernel<<<2048,256,0,stream>>>(x, ln1_g+l*256, ln1_b+l*256, hbf);
    gemm_mfma<256,768,0,64,64><<<dim3(12,32),256,0,stream>>>(
        hbf, WqkvT + (size_t)l*196608, nullptr, nullptr, qkvbf);
    rope_apply_bf<<<2048,256,0,stream>>>(qkvbf, sint, cost, qbf, kbf, vbf);
    rel_pre<<<513,256,0,stream>>>(coords, vel, relW1+l*320, relb1+l*64,
                                  relW2+l*512, Arel, A2rel, W2Tbf);
    rel_fused5<<<2048,256,0,stream>>>(coords, Arel, A2rel, relW1+l*320,
                                      W2Tbf, relb2+l*8, relbf);
    attn_mfma<<<512,256,0,stream>>>(qbf, kbf, vbf, relbf, attbf);
    gemm_mfma<256,256,1,64,32><<<dim3(8,32),256,0,stream>>>(
        attbf, WoutT + (size_t)l*65536, bout+l*256, x, x);
    ln_kernel<<<2048,256,0,stream>>>(x, ln2_g+l*256, ln2_b+l*256, hbf);
    gemm_mfma<256,1024,2,64,64><<<dim3(16,32),256,0,stream>>>(
        hbf, Wf1T + (size_t)l*262144, bf1+l*1024, nullptr, midbf);
    gemm_mfma<1024,256,1,64,32><<<dim3(8,32),256,0,stream>>>(
        midbf, Wf2T + (size_t)l*262144, bf2+l*256, x, x);
  }
}

// Round 11
// 275.309 us; speedup vs baseline: 1.2167x; 1.2167x over previous
//
#include <hip/hip_runtime.h>
#include <math.h>

#define BN_ 2
#define NN 1024
#define DDIM 256
#define HH 8
#define HDIM 32
#define FFD 1024
#define EPSV 1e-5f
#define SCALEV 0.17677669529663687f
#define LPAD 72

typedef __attribute__((ext_vector_type(8))) short s16x8;
typedef __attribute__((ext_vector_type(4))) float f32x4;

__device__ __forceinline__ float gelu_f(float x){
  return 0.5f*x*(1.0f+erff(x*0.70710678118654752f));
}
__device__ __forceinline__ unsigned int pack_bf16(float lo, float hi){
  unsigned int ul = __float_as_uint(lo), uh = __float_as_uint(hi);
  ul += 0x7fff + ((ul>>16)&1);
  uh += 0x7fff + ((uh>>16)&1);
  return (ul>>16) | (uh & 0xffff0000u);
}
__device__ __forceinline__ unsigned short f2bf(float x){
  unsigned int u = __float_as_uint(x);
  u += 0x7fff + ((u>>16)&1);
  return (unsigned short)(u>>16);
}
__device__ __forceinline__ float bf2f(unsigned short u){
  return __uint_as_float(((unsigned int)u)<<16);
}
// truncation-pack two f32 -> one dword of 2 bf16 (v_perm_b32)
__device__ __forceinline__ unsigned int packtr(float lo, float hi){
  return __builtin_amdgcn_perm(__float_as_uint(hi), __float_as_uint(lo), 0x07060302u);
}
__device__ __forceinline__ f32x4 mfma16(s16x8 a, s16x8 b, f32x4 c){
  return __builtin_amdgcn_mfma_f32_16x16x32_bf16(a,b,c,0,0,0);
}
// gelu Taylor poly (|t| small): 0.5t + t^2*(c0 + c1 u + c2 u^2), u=t^2
__device__ __forceinline__ float gpoly(float t){
  float u = t*t;
  float p = fmaf(u, 0.0099735570f, -0.0664904395f);
  p = fmaf(u, p, 0.3989422804f);
  return fmaf(u, p, 0.5f*t);
}
__device__ __forceinline__ void g4(float d, float4 a, float4 w4, float4 t4, float* o){
  o[0] = gpoly(fmaf(d, w4.x, a.x - t4.x));
  o[1] = gpoly(fmaf(d, w4.y, a.y - t4.y));
  o[2] = gpoly(fmaf(d, w4.z, a.z - t4.z));
  o[3] = gpoly(fmaf(d, w4.w, a.w - t4.w));
}

// ---------------- LayerNorm: f32 in, bf16 out --------------------------------
__global__ __launch_bounds__(256) void ln_kernel(const float* __restrict__ x,
    const float* __restrict__ g, const float* __restrict__ b,
    unsigned short* __restrict__ out){
  int row = blockIdx.x, tid = threadIdx.x;
  float val = x[(size_t)row*DDIM + tid];
  float s = val;
  #pragma unroll
  for (int o=32;o;o>>=1) s += __shfl_xor(s,o);
  __shared__ float sb[4], sb2[4];
  if ((tid&63)==0) sb[tid>>6]=s;
  __syncthreads();
  float mean = (sb[0]+sb[1]+sb[2]+sb[3]) * (1.0f/DDIM);
  float d = val-mean;
  float vs = d*d;
  #pragma unroll
  for (int o=32;o;o>>=1) vs += __shfl_xor(vs,o);
  if ((tid&63)==0) sb2[tid>>6]=vs;
  __syncthreads();
  float var = (sb2[0]+sb2[1]+sb2[2]+sb2[3]) * (1.0f/DDIM);
  out[(size_t)row*DDIM + tid] = f2bf(d*rsqrtf(var+EPSV)*g[tid]+b[tid]);
}

// ---------------- RoPE tables -------------------------------------------------
__global__ __launch_bounds__(256) void rope_table(float* __restrict__ sint, float* __restrict__ cost){
  int idx = blockIdx.x*256+threadIdx.x;   // 16384
  int i = idx >> 4, d = idx & 15;
  float freq = (float)i * powf(10000.0f, -(float)d/16.0f);
  sint[idx]=sinf(freq); cost[idx]=cosf(freq);
}

// ---------------- weight convert+transpose f32(K,NC) -> bf16 WT(NC,K) --------
__global__ __launch_bounds__(256) void wt_convert(const float* __restrict__ in,
    unsigned short* __restrict__ out, int K, int NC, int scaleCols, float scaleVal){
  __shared__ float tile[32][33];
  int tn0 = blockIdx.x*32;
  int tk0 = blockIdx.y*32;
  size_t loff = (size_t)blockIdx.z * K * NC;
  int t = threadIdx.x;
  int col = t & 31, rr = t >> 5;
  #pragma unroll
  for (int i=0;i<4;++i){
    int row = rr + i*8;
    tile[row][col] = in[loff + (size_t)(tk0+row)*NC + tn0+col];
  }
  __syncthreads();
  #pragma unroll
  for (int i=0;i<4;++i){
    int row = rr + i*8;
    int n = tn0 + row;
    float s = (n < scaleCols) ? scaleVal : 1.0f;
    out[loff + (size_t)n*K + tk0 + col] = f2bf(tile[col][row]*s);
  }
}

// ------------- split qkv + rope (bf16 in/out) --------------------------------
__global__ __launch_bounds__(256) void rope_apply_bf(const unsigned short* __restrict__ qkv,
    const float* __restrict__ sint, const float* __restrict__ cost,
    unsigned short* __restrict__ q, unsigned short* __restrict__ k,
    unsigned short* __restrict__ v){
  int row = blockIdx.x;                 // b*1024 + i
  int b = row>>10, i = row&1023;
  int tid = threadIdx.x; int h = tid>>5, d = tid&31;
  const unsigned short* base = qkv + (size_t)row*768;
  size_t oidx = (((size_t)((b<<3)+h)<<10) + i)*32 + d;
  v[oidx] = base[512 + h*32 + d];
  int dd = (d<16) ? d : d-16;
  float s = sint[i*16+dd], c = cost[i*16+dd];
  float q1 = bf2f(base[h*32+dd]), q2 = bf2f(base[h*32+dd+16]);
  q[oidx] = f2bf((d<16) ? (q1*c - q2*s) : (q2*c + q1*s));
  float k1 = bf2f(base[256+h*32+dd]), k2 = bf2f(base[256+h*32+dd+16]);
  k[oidx] = f2bf((d<16) ? (k1*c - k2*s) : (k2*c + k1*s));
}

// ------------- rel precompute: per-node separable parts + W2T ----------------
// blocks 0..511: A[node][64] (=b1+bv), A2[node][64] (=bv). block 512: W2T[16][64]
__global__ __launch_bounds__(256) void rel_pre(const float* __restrict__ coords,
    const float* __restrict__ vel, const float* __restrict__ W1,
    const float* __restrict__ b1, const float* __restrict__ W2,
    float* __restrict__ A, float* __restrict__ A2, unsigned short* __restrict__ W2T){
  if (blockIdx.x == 512){
    int t = threadIdx.x;
    #pragma unroll
    for (int e=0;e<4;++e){
      int idx = t*4+e;              // n*64 + k
      int n = idx>>6, kk = idx&63;
      W2T[idx] = (n<8) ? f2bf(W2[kk*8+n]) : 0;
    }
    return;
  }
  int gid = blockIdx.x*256 + threadIdx.x;  // 2048*64
  int node = gid >> 6, r = gid & 63;
  float c0 = coords[node*2], c1 = coords[node*2+1];
  float v0 = vel[node*2],    v1 = vel[node*2+1];
  float bv = c0*W1[r] + c1*W1[64+r] + v0*W1[192+r] + v1*W1[256+r];
  A[gid] = b1[r] + bv;
  A2[gid] = bv;
}

// ------------- rel fused v6: 2 i's per block, A-frag layout, no LDS ----------
// Block = (b, i-pair); 4 waves; wave w covers j in [w*256,+256) as 16 subtiles
// of 16 j. Lane l: j = j0+(l&15), r in {lg*8..+7, 32+lg*8..+7}.
// A2/coords loads per subtile are shared by both i's (halved loads/pair).
__global__ __launch_bounds__(256, 4) void rel_fused6(const float* __restrict__ coords,
    const float* __restrict__ A, const float* __restrict__ A2,
    const float* __restrict__ W1, const unsigned short* __restrict__ W2T,
    const float* __restrict__ b2, unsigned short* __restrict__ relbf){
  const int tid = threadIdx.x;
  const int bid = blockIdx.x;            // 1024
  const int b = bid >> 9;
  const int ia = (bid & 511) * 2;        // this block: rows ia, ia+1
  const int w = tid>>6, l = tid&63, lc = l&15, lg = l>>4;
  const int nodea = (b<<10) + ia;
  float2 cia = *(const float2*)(coords + (size_t)nodea*2);
  float2 cib = *(const float2*)(coords + (size_t)nodea*2 + 2);

  // per-lane r-slice invariants
  const float* Apa = A + (size_t)nodea*64 + lg*8;
  const float4 aA = *(const float4*)(Apa);
  const float4 aB = *(const float4*)(Apa+4);
  const float4 aC = *(const float4*)(Apa+32);
  const float4 aD = *(const float4*)(Apa+36);
  const float4 bA = *(const float4*)(Apa+64);
  const float4 bB = *(const float4*)(Apa+68);
  const float4 bC = *(const float4*)(Apa+96);
  const float4 bD = *(const float4*)(Apa+100);
  const float* Wp = W1 + 128 + lg*8;
  const float4 wA = *(const float4*)(Wp);
  const float4 wB = *(const float4*)(Wp+4);
  const float4 wC = *(const float4*)(Wp+32);
  const float4 wD = *(const float4*)(Wp+36);

  // B-fragment of W2 (n=lc -> h, k=lg*8+e -> r)
  const s16x8 bf0 = *(const s16x8*)&W2T[lc*64 + lg*8];
  const s16x8 bf1 = *(const s16x8*)&W2T[lc*64 + 32 + lg*8];
  const float b2v = (lc<8) ? b2[lc] : 0.f;

  const float* cb = coords + (size_t)((b<<10) + w*256 + lc)*2;
  const float* ab = A2 + (size_t)((b<<10) + w*256 + lc)*64 + lg*8;
  unsigned short* oba = relbf + ((size_t)b<<23) + ((size_t)ia<<10)
                      + ((size_t)(lc&7)<<20) + (unsigned)(w*256 + lg*4);

  for (int st=0; st<16; ++st){
    const float* ap = ab + st*1024;
    float2 cj = *(const float2*)(cb + st*32);
    float4 q0 = *(const float4*)(ap);
    float4 q1 = *(const float4*)(ap+4);
    float4 q2 = *(const float4*)(ap+32);
    float4 q3 = *(const float4*)(ap+36);
    // ---- i_a ----
    {
      float dx = cia.x-cj.x, dy = cia.y-cj.y;
      float d = sqrtf(fmaf(dx,dx,dy*dy));
      float gg[16];
      g4(d, aA, wA, q0, gg);
      g4(d, aB, wB, q1, gg+4);
      g4(d, aC, wC, q2, gg+8);
      g4(d, aD, wD, q3, gg+12);
      union { unsigned int u[4]; s16x8 v; } p0, p1;
      p0.u[0]=packtr(gg[0],gg[1]);  p0.u[1]=packtr(gg[2],gg[3]);
      p0.u[2]=packtr(gg[4],gg[5]);  p0.u[3]=packtr(gg[6],gg[7]);
      p1.u[0]=packtr(gg[8],gg[9]);  p1.u[1]=packtr(gg[10],gg[11]);
      p1.u[2]=packtr(gg[12],gg[13]);p1.u[3]=packtr(gg[14],gg[15]);
      f32x4 z; z[0]=0.f; z[1]=0.f; z[2]=0.f; z[3]=0.f;
      z = mfma16(p0.v, bf0, z);
      z = mfma16(p1.v, bf1, z);
      if (lc < 8){
        unsigned short* op = oba + st*16;
        *(unsigned int*)op     = pack_bf16(z[0]+b2v, z[1]+b2v);
        *(unsigned int*)(op+2) = pack_bf16(z[2]+b2v, z[3]+b2v);
      }
    }
    // ---- i_b (same tv/cj loads) ----
    {
      float dx = cib.x-cj.x, dy = cib.y-cj.y;
      float d = sqrtf(fmaf(dx,dx,dy*dy));
      float gg[16];
      g4(d, bA, wA, q0, gg);
      g4(d, bB, wB, q1, gg+4);
      g4(d, bC, wC, q2, gg+8);
      g4(d, bD, wD, q3, gg+12);
      union { unsigned int u[4]; s16x8 v; } p0, p1;
      p0.u[0]=packtr(gg[0],gg[1]);  p0.u[1]=packtr(gg[2],gg[3]);
      p0.u[2]=packtr(gg[4],gg[5]);  p0.u[3]=packtr(gg[6],gg[7]);
      p1.u[0]=packtr(gg[8],gg[9]);  p1.u[1]=packtr(gg[10],gg[11]);
      p1.u[2]=packtr(gg[12],gg[13]);p1.u[3]=packtr(gg[14],gg[15]);
      f32x4 z; z[0]=0.f; z[1]=0.f; z[2]=0.f; z[3]=0.f;
      z = mfma16(p0.v, bf0, z);
      z = mfma16(p1.v, bf1, z);
      if (lc < 8){
        unsigned short* op = oba + 1024 + st*16;
        *(unsigned int*)op     = pack_bf16(z[0]+b2v, z[1]+b2v);
        *(unsigned int*)(op+2) = pack_bf16(z[2]+b2v, z[3]+b2v);
      }
    }
  }
}

// ------------- MFMA flash attention (all-bf16 inputs) -------------------------
__global__ __launch_bounds__(256) void attn_mfma(
    const unsigned short* __restrict__ q, const unsigned short* __restrict__ kk,
    const unsigned short* __restrict__ vv, const unsigned short* __restrict__ relbf,
    unsigned short* __restrict__ out){
  int bh = blockIdx.x >> 5;
  int i0 = (blockIdx.x & 31) * 32;
  int tid = threadIdx.x;
  int w  = tid >> 6;
  int l  = tid & 63;
  int lc = l & 15;
  int lg = l >> 4;

  __shared__ __align__(16) unsigned short VT[2][32*LPAD];
  __shared__ __align__(16) unsigned short PL[2][32*LPAD];
  __shared__ __align__(16) float wmaxs[2][32][4];
  __shared__ __align__(16) float wsums[2][32][4];
  __shared__ float mld[2][32];
  __shared__ float lld[2][32];

  const unsigned short* qb = q + ((size_t)(bh<<10) + i0)*32;
  const unsigned short* kb = kk + ((size_t)bh<<15);
  const unsigned short* vb = vv + ((size_t)bh<<15);
  const unsigned short* relb = relbf + ((size_t)bh<<20) + ((size_t)i0<<10);

  s16x8 qf0 = *(const s16x8*)(qb + (size_t)lc*32 + lg*8);
  s16x8 qf1 = *(const s16x8*)(qb + (size_t)(16+lc)*32 + lg*8);

  if (tid < 32){ mld[0][tid] = -1e30f; lld[0][tid] = 0.f; }

  f32x4 acc; acc[0]=0.f; acc[1]=0.f; acc[2]=0.f; acc[3]=0.f;
  const int dh  = w & 1;
  const int pih = w >> 1;

  for (int t=0; t<16; ++t){
    const int c = t & 1, nx = c ^ 1;
    const int j0 = t*64;
    {
      int jj = tid & 63, d0 = (tid >> 6)*8;
      s16x8 v8 = *(const s16x8*)(vb + (size_t)(j0+jj)*32 + d0);
      unsigned short* dst = VT[c];
      #pragma unroll
      for (int e=0;e<8;++e) dst[(d0+e)*LPAD + jj] = (unsigned short)v8[e];
    }
    s16x8 kf = *(const s16x8*)(kb + (size_t)(j0 + w*16 + lc)*32 + lg*8);
    f32x4 z; z[0]=0.f; z[1]=0.f; z[2]=0.f; z[3]=0.f;
    f32x4 s0 = mfma16(qf0, kf, z);
    f32x4 s1 = mfma16(qf1, kf, z);
    float sv0[4], sv1[4], rm0[4], rm1[4];
    const int jc = j0 + w*16 + lc;
    #pragma unroll
    for (int r=0;r<4;++r){
      int row0 = lg*4 + r;
      sv0[r] = s0[r] + bf2f(relb[(size_t)row0*1024 + jc]);
      sv1[r] = s1[r] + bf2f(relb[(size_t)(row0+16)*1024 + jc]);
      float a0 = sv0[r], a1 = sv1[r];
      #pragma unroll
      for (int o=1;o<16;o<<=1){
        a0 = fmaxf(a0, __shfl_xor(a0,o));
        a1 = fmaxf(a1, __shfl_xor(a1,o));
      }
      rm0[r]=a0; rm1[r]=a1;
    }
    if (lc == 0){
      #pragma unroll
      for (int r=0;r<4;++r){
        wmaxs[c][lg*4+r][w]    = rm0[r];
        wmaxs[c][lg*4+r+16][w] = rm1[r];
      }
    }
    __syncthreads();
    float mn0[4], mn1[4], sc0[4], sc1[4];
    #pragma unroll
    for (int r=0;r<4;++r){
      int row0 = lg*4+r;
      float4 wm0 = *(const float4*)wmaxs[c][row0];
      float4 wm1 = *(const float4*)wmaxs[c][row0+16];
      float mo0 = mld[c][row0], mo1 = mld[c][row0+16];
      float t0 = fmaxf(fmaxf(wm0.x,wm0.y), fmaxf(wm0.z,wm0.w));
      float t1 = fmaxf(fmaxf(wm1.x,wm1.y), fmaxf(wm1.z,wm1.w));
      mn0[r] = fmaxf(mo0, t0);  mn1[r] = fmaxf(mo1, t1);
      sc0[r] = __expf(mo0 - mn0[r]); sc1[r] = __expf(mo1 - mn1[r]);
    }
    float ps0[4], ps1[4];
    #pragma unroll
    for (int r=0;r<4;++r){
      int row0 = lg*4+r;
      float p0 = __expf(sv0[r]-mn0[r]);
      float p1 = __expf(sv1[r]-mn1[r]);
      PL[c][(size_t)row0*LPAD + w*16 + lc]      = f2bf(p0);
      PL[c][(size_t)(row0+16)*LPAD + w*16 + lc] = f2bf(p1);
      #pragma unroll
      for (int o=1;o<16;o<<=1){
        p0 += __shfl_xor(p0,o);
        p1 += __shfl_xor(p1,o);
      }
      ps0[r]=p0; ps1[r]=p1;
    }
    if (lc == 0){
      #pragma unroll
      for (int r=0;r<4;++r){
        wsums[c][lg*4+r][w]    = ps0[r];
        wsums[c][lg*4+r+16][w] = ps1[r];
      }
    }
    #pragma unroll
    for (int r=0;r<4;++r){
      float s = (pih==0) ? sc0[r] : sc1[r];
      acc[r] *= s;
    }
    __syncthreads();
    #pragma unroll
    for (int kc=0;kc<2;++kc){
      s16x8 pa = *(const s16x8*)&PL[c][(size_t)(pih*16 + lc)*LPAD + kc*32 + lg*8];
      s16x8 vf = *(const s16x8*)&VT[c][(size_t)(dh*16 + lc)*LPAD + kc*32 + lg*8];
      acc = mfma16(pa, vf, acc);
    }
    if (w==0 && lc==0){
      #pragma unroll
      for (int r=0;r<4;++r){
        int row0 = lg*4+r;
        float4 u0 = *(const float4*)wsums[c][row0];
        float4 u1 = *(const float4*)wsums[c][row0+16];
        lld[nx][row0]    = lld[c][row0]*sc0[r]    + (u0.x+u0.y+u0.z+u0.w);
        lld[nx][row0+16] = lld[c][row0+16]*sc1[r] + (u1.x+u1.y+u1.z+u1.w);
        mld[nx][row0]    = mn0[r];
        mld[nx][row0+16] = mn1[r];
      }
    }
  }
  __syncthreads();
  int b = bh>>3, hh = bh&7;
  #pragma unroll
  for (int r=0;r<4;++r){
    int row = pih*16 + lg*4 + r;
    float li = lld[0][row];
    out[((size_t)((b<<10)+i0+row))*256 + hh*32 + dh*16 + lc] = f2bf(acc[r]/li);
  }
}

// ------------- MFMA GEMM: C[M,NC] = A[M,K] @ W[K,NC], A bf16, WT bf16(NC,K) --
template<int K, int NC, int EPI, int BM, int BNt>
__global__ __launch_bounds__(256) void gemm_mfma(
    const unsigned short* __restrict__ Aa, const unsigned short* __restrict__ WT,
    const float* __restrict__ bias, const float* __restrict__ resid,
    void* __restrict__ outv){
  constexpr int WMm = BM/2, WNn = BNt/2;
  constexpr int FM = WMm/16, FN = WNn/16;
  constexpr int LP = 40;
  __shared__ __align__(16) unsigned short As[BM*LP];
  __shared__ __align__(16) unsigned short Bs[BNt*LP];
  const int tid = threadIdx.x;
  const int w = tid>>6, l = tid&63, lc = l&15, lg = l>>4;
  const int wm = w&1, wn = w>>1;
  const int n0 = blockIdx.x*BNt, m0 = blockIdx.y*BM;
  f32x4 acc[FM][FN];
  #pragma unroll
  for (int a=0;a<FM;++a)
    #pragma unroll
    for (int c=0;c<FN;++c){ acc[a][c][0]=0.f; acc[a][c][1]=0.f; acc[a][c][2]=0.f; acc[a][c][3]=0.f; }

  for (int k0=0; k0<K; k0+=32){
    __syncthreads();
    if constexpr (BM==64){
      int row = tid>>2, cg = tid&3;
      *(s16x8*)&As[row*LP+cg*8] = *(const s16x8*)&Aa[(size_t)(m0+row)*K + k0 + cg*8];
    } else {
      int row = tid>>3, cg = tid&7;
      *(ushort4*)&As[row*LP+cg*4] = *(const ushort4*)&Aa[(size_t)(m0+row)*K + k0 + cg*4];
    }
    if constexpr (BNt==64){
      int row = tid>>2, cg = tid&3;
      *(s16x8*)&Bs[row*LP+cg*8] = *(const s16x8*)&WT[(size_t)(n0+row)*K + k0 + cg*8];
    } else {
      int row = tid>>3, cg = tid&7;
      *(ushort4*)&Bs[row*LP+cg*4] = *(const ushort4*)&WT[(size_t)(n0+row)*K + k0 + cg*4];
    }
    __syncthreads();
    s16x8 af[FM], bv[FN];
    #pragma unroll
    for (int a=0;a<FM;++a) af[a] = *(const s16x8*)&As[(wm*WMm + a*16 + lc)*LP + lg*8];
    #pragma unroll
    for (int c=0;c<FN;++c) bv[c] = *(const s16x8*)&Bs[(wn*WNn + c*16 + lc)*LP + lg*8];
    #pragma unroll
    for (int a=0;a<FM;++a)
      #pragma unroll
      for (int c=0;c<FN;++c) acc[a][c] = mfma16(af[a], bv[c], acc[a][c]);
  }
  #pragma unroll
  for (int a=0;a<FM;++a){
    #pragma unroll
    for (int c=0;c<FN;++c){
      int n = n0 + wn*WNn + c*16 + lc;
      float bvv = (EPI!=0) ? bias[n] : 0.f;
      #pragma unroll
      for (int r=0;r<4;++r){
        int m = m0 + wm*WMm + a*16 + lg*4 + r;
        float vv = acc[a][c][r];
        if constexpr (EPI==0){
          ((unsigned short*)outv)[(size_t)m*NC + n] = f2bf(vv);
        } else if constexpr (EPI==1){
          ((float*)outv)[(size_t)m*NC + n] = vv + bvv + resid[(size_t)m*NC + n];
        } else {
          ((unsigned short*)outv)[(size_t)m*NC + n] = f2bf(gelu_f(vv + bvv));
        }
      }
    }
  }
}

extern "C" void kernel_launch(void* const* d_in, const int* in_sizes, int n_in,
                              void* d_out, int out_size, void* d_ws, size_t ws_size,
                              hipStream_t stream){
  const float* x_in  = (const float*)d_in[0];
  const float* coords= (const float*)d_in[1];
  const float* vel   = (const float*)d_in[2];
  const float* ln1_g = (const float*)d_in[3];
  const float* ln1_b = (const float*)d_in[4];
  const float* Wqkv  = (const float*)d_in[5];
  const float* relW1 = (const float*)d_in[6];
  const float* relb1 = (const float*)d_in[7];
  const float* relW2 = (const float*)d_in[8];
  const float* relb2 = (const float*)d_in[9];
  const float* Wout  = (const float*)d_in[10];
  const float* bout  = (const float*)d_in[11];
  const float* ln2_g = (const float*)d_in[12];
  const float* ln2_b = (const float*)d_in[13];
  const float* Wf1   = (const float*)d_in[14];
  const float* bf1   = (const float*)d_in[15];
  const float* Wf2   = (const float*)d_in[16];
  const float* bf2   = (const float*)d_in[17];

  float* x = (float*)d_out;
  unsigned short* us = (unsigned short*)d_ws;
  unsigned short* hbf   = us;                    // 524288
  unsigned short* qkvbf = hbf   + 524288;        // 1572864
  unsigned short* qbf   = qkvbf + 1572864;       // 524288
  unsigned short* kbf   = qbf   + 524288;        // 524288
  unsigned short* vbf   = kbf   + 524288;        // 524288
  unsigned short* attbf = vbf   + 524288;        // 524288
  unsigned short* midbf = attbf + 524288;        // 2097152
  unsigned short* relbf = midbf + 2097152;       // 16777216
  unsigned short* WqkvT = relbf + 16777216;      // 393216
  unsigned short* WoutT = WqkvT + 393216;        // 131072
  unsigned short* Wf1T  = WoutT + 131072;        // 524288
  unsigned short* Wf2T  = Wf1T  + 524288;        // 524288
  unsigned short* W2Tbf = Wf2T  + 524288;        // 1024
  float* Arel  = (float*)(W2Tbf + 1024);         // 131072
  float* A2rel = Arel + 131072;                  // 131072
  float* sint  = A2rel + 131072;                 // 16384
  float* cost  = sint + 16384;                   // 16384

  hipMemcpyAsync(x, x_in, sizeof(float)*524288, hipMemcpyDeviceToDevice, stream);
  rope_table<<<64,256,0,stream>>>(sint,cost);
  wt_convert<<<dim3(24,8,2),256,0,stream>>>(Wqkv, WqkvT, 256, 768, 256, SCALEV);
  wt_convert<<<dim3(8,8,2),256,0,stream>>>(Wout, WoutT, 256, 256, 0, 1.0f);
  wt_convert<<<dim3(32,8,2),256,0,stream>>>(Wf1, Wf1T, 256, 1024, 0, 1.0f);
  wt_convert<<<dim3(8,32,2),256,0,stream>>>(Wf2, Wf2T, 1024, 256, 0, 1.0f);

  for (int l=0;l<2;++l){
    ln_kernel<<<2048,256,0,stream>>>(x, ln1_g+l*256, ln1_b+l*256, hbf);
    gemm_mfma<256,768,0,64,64><<<dim3(12,32),256,0,stream>>>(
        hbf, WqkvT + (size_t)l*196608, nullptr, nullptr, qkvbf);
    rope_apply_bf<<<2048,256,0,stream>>>(qkvbf, sint, cost, qbf, kbf, vbf);
    rel_pre<<<513,256,0,stream>>>(coords, vel, relW1+l*320, relb1+l*64,
                                  relW2+l*512, Arel, A2rel, W2Tbf);
    rel_fused6<<<1024,256,0,stream>>>(coords, Arel, A2rel, relW1+l*320,
                                      W2Tbf, relb2+l*8, relbf);
    attn_mfma<<<512,256,0,stream>>>(qbf, kbf, vbf, relbf, attbf);
    gemm_mfma<256,256,1,32,32><<<dim3(8,64),256,0,stream>>>(
        attbf, WoutT + (size_t)l*65536, bout+l*256, x, x);
    ln_kernel<<<2048,256,0,stream>>>(x, ln2_g+l*256, ln2_b+l*256, hbf);
    gemm_mfma<256,1024,2,64,64><<<dim3(16,32),256,0,stream>>>(
        hbf, Wf1T + (size_t)l*262144, bf1+l*1024, nullptr, midbf);
    gemm_mfma<1024,256,1,32,32><<<dim3(8,64),256,0,stream>>>(
        midbf, Wf2T + (size_t)l*262144, bf2+l*256, x, x);
  }
}

// Round 12
// 223.789 us; speedup vs baseline: 1.4968x; 1.2302x over previous
//
#include <hip/hip_runtime.h>
#include <math.h>

#define BN_ 2
#define NN 1024
#define DDIM 256
#define HH 8
#define HDIM 32
#define FFD 1024
#define EPSV 1e-5f
#define SCALEV 0.17677669529663687f

typedef __attribute__((ext_vector_type(8))) short s16x8;
typedef __attribute__((ext_vector_type(4))) short s16x4;
typedef __attribute__((ext_vector_type(4))) float f32x4;

__device__ __forceinline__ float gelu_f(float x){
  return 0.5f*x*(1.0f+erff(x*0.70710678118654752f));
}
__device__ __forceinline__ unsigned int pack_bf16(float lo, float hi){
  unsigned int ul = __float_as_uint(lo), uh = __float_as_uint(hi);
  ul += 0x7fff + ((ul>>16)&1);
  uh += 0x7fff + ((uh>>16)&1);
  return (ul>>16) | (uh & 0xffff0000u);
}
__device__ __forceinline__ unsigned short f2bf(float x){
  unsigned int u = __float_as_uint(x);
  u += 0x7fff + ((u>>16)&1);
  return (unsigned short)(u>>16);
}
__device__ __forceinline__ float bf2f(unsigned short u){
  return __uint_as_float(((unsigned int)u)<<16);
}
__device__ __forceinline__ unsigned int packtr(float lo, float hi){
  return __builtin_amdgcn_perm(__float_as_uint(hi), __float_as_uint(lo), 0x07060302u);
}
__device__ __forceinline__ f32x4 mfma16(s16x8 a, s16x8 b, f32x4 c){
  return __builtin_amdgcn_mfma_f32_16x16x32_bf16(a,b,c,0,0,0);
}
__device__ __forceinline__ float gpoly(float t){
  float u = t*t;
  float p = fmaf(u, 0.0099735570f, -0.0664904395f);
  p = fmaf(u, p, 0.3989422804f);
  return fmaf(u, p, 0.5f*t);
}
__device__ __forceinline__ void g4(float d, float4 a, float4 w4, float4 t4, float* o){
  o[0] = gpoly(fmaf(d, w4.x, a.x - t4.x));
  o[1] = gpoly(fmaf(d, w4.y, a.y - t4.y));
  o[2] = gpoly(fmaf(d, w4.z, a.z - t4.z));
  o[3] = gpoly(fmaf(d, w4.w, a.w - t4.w));
}

// ---------------- LayerNorm: f32 in, bf16 out --------------------------------
__global__ __launch_bounds__(256) void ln_kernel(const float* __restrict__ x,
    const float* __restrict__ g, const float* __restrict__ b,
    unsigned short* __restrict__ out){
  int row = blockIdx.x, tid = threadIdx.x;
  float val = x[(size_t)row*DDIM + tid];
  float s = val;
  #pragma unroll
  for (int o=32;o;o>>=1) s += __shfl_xor(s,o);
  __shared__ float sb[4], sb2[4];
  if ((tid&63)==0) sb[tid>>6]=s;
  __syncthreads();
  float mean = (sb[0]+sb[1]+sb[2]+sb[3]) * (1.0f/DDIM);
  float d = val-mean;
  float vs = d*d;
  #pragma unroll
  for (int o=32;o;o>>=1) vs += __shfl_xor(vs,o);
  if ((tid&63)==0) sb2[tid>>6]=vs;
  __syncthreads();
  float var = (sb2[0]+sb2[1]+sb2[2]+sb2[3]) * (1.0f/DDIM);
  out[(size_t)row*DDIM + tid] = f2bf(d*rsqrtf(var+EPSV)*g[tid]+b[tid]);
}

// ---------------- RoPE tables -------------------------------------------------
__global__ __launch_bounds__(256) void rope_table(float* __restrict__ sint, float* __restrict__ cost){
  int idx = blockIdx.x*256+threadIdx.x;   // 16384
  int i = idx >> 4, d = idx & 15;
  float freq = (float)i * powf(10000.0f, -(float)d/16.0f);
  sint[idx]=sinf(freq); cost[idx]=cosf(freq);
}

// ---------------- weight convert+transpose f32(K,NC) -> bf16 WT(NC,K) --------
__global__ __launch_bounds__(256) void wt_convert(const float* __restrict__ in,
    unsigned short* __restrict__ out, int K, int NC, int scaleCols, float scaleVal){
  __shared__ float tile[32][33];
  int tn0 = blockIdx.x*32;
  int tk0 = blockIdx.y*32;
  size_t loff = (size_t)blockIdx.z * K * NC;
  int t = threadIdx.x;
  int col = t & 31, rr = t >> 5;
  #pragma unroll
  for (int i=0;i<4;++i){
    int row = rr + i*8;
    tile[row][col] = in[loff + (size_t)(tk0+row)*NC + tn0+col];
  }
  __syncthreads();
  #pragma unroll
  for (int i=0;i<4;++i){
    int row = rr + i*8;
    int n = tn0 + row;
    float s = (n < scaleCols) ? scaleVal : 1.0f;
    out[loff + (size_t)n*K + tk0 + col] = f2bf(tile[col][row]*s);
  }
}

// ------------- split qkv + rope (bf16 in/out) --------------------------------
__global__ __launch_bounds__(256) void rope_apply_bf(const unsigned short* __restrict__ qkv,
    const float* __restrict__ sint, const float* __restrict__ cost,
    unsigned short* __restrict__ q, unsigned short* __restrict__ k,
    unsigned short* __restrict__ v){
  int row = blockIdx.x;                 // b*1024 + i
  int b = row>>10, i = row&1023;
  int tid = threadIdx.x; int h = tid>>5, d = tid&31;
  const unsigned short* base = qkv + (size_t)row*768;
  size_t oidx = (((size_t)((b<<3)+h)<<10) + i)*32 + d;
  v[oidx] = base[512 + h*32 + d];
  int dd = (d<16) ? d : d-16;
  float s = sint[i*16+dd], c = cost[i*16+dd];
  float q1 = bf2f(base[h*32+dd]), q2 = bf2f(base[h*32+dd+16]);
  q[oidx] = f2bf((d<16) ? (q1*c - q2*s) : (q2*c + q1*s));
  float k1 = bf2f(base[256+h*32+dd]), k2 = bf2f(base[256+h*32+dd+16]);
  k[oidx] = f2bf((d<16) ? (k1*c - k2*s) : (k2*c + k1*s));
}

// ------------- rel precompute: per-node separable parts + W2T ----------------
__global__ __launch_bounds__(256) void rel_pre(const float* __restrict__ coords,
    const float* __restrict__ vel, const float* __restrict__ W1,
    const float* __restrict__ b1, const float* __restrict__ W2,
    float* __restrict__ A, float* __restrict__ A2, unsigned short* __restrict__ W2T){
  if (blockIdx.x == 512){
    int t = threadIdx.x;
    #pragma unroll
    for (int e=0;e<4;++e){
      int idx = t*4+e;              // n*64 + k
      int n = idx>>6, kk = idx&63;
      W2T[idx] = (n<8) ? f2bf(W2[kk*8+n]) : 0;
    }
    return;
  }
  int gid = blockIdx.x*256 + threadIdx.x;  // 2048*64
  int node = gid >> 6, r = gid & 63;
  float c0 = coords[node*2], c1 = coords[node*2+1];
  float v0 = vel[node*2],    v1 = vel[node*2+1];
  float bv = c0*W1[r] + c1*W1[64+r] + v0*W1[192+r] + v1*W1[256+r];
  A[gid] = b1[r] + bv;
  A2[gid] = bv;
}

// ------------- rel fused v6: 2 i's per block, A-frag layout, no LDS ----------
__global__ __launch_bounds__(256, 4) void rel_fused6(const float* __restrict__ coords,
    const float* __restrict__ A, const float* __restrict__ A2,
    const float* __restrict__ W1, const unsigned short* __restrict__ W2T,
    const float* __restrict__ b2, unsigned short* __restrict__ relbf){
  const int tid = threadIdx.x;
  const int bid = blockIdx.x;            // 1024
  const int b = bid >> 9;
  const int ia = (bid & 511) * 2;        // this block: rows ia, ia+1
  const int w = tid>>6, l = tid&63, lc = l&15, lg = l>>4;
  const int nodea = (b<<10) + ia;
  float2 cia = *(const float2*)(coords + (size_t)nodea*2);
  float2 cib = *(const float2*)(coords + (size_t)nodea*2 + 2);

  const float* Apa = A + (size_t)nodea*64 + lg*8;
  const float4 aA = *(const float4*)(Apa);
  const float4 aB = *(const float4*)(Apa+4);
  const float4 aC = *(const float4*)(Apa+32);
  const float4 aD = *(const float4*)(Apa+36);
  const float4 bA = *(const float4*)(Apa+64);
  const float4 bB = *(const float4*)(Apa+68);
  const float4 bC = *(const float4*)(Apa+96);
  const float4 bD = *(const float4*)(Apa+100);
  const float* Wp = W1 + 128 + lg*8;
  const float4 wA = *(const float4*)(Wp);
  const float4 wB = *(const float4*)(Wp+4);
  const float4 wC = *(const float4*)(Wp+32);
  const float4 wD = *(const float4*)(Wp+36);

  const s16x8 bf0 = *(const s16x8*)&W2T[lc*64 + lg*8];
  const s16x8 bf1 = *(const s16x8*)&W2T[lc*64 + 32 + lg*8];
  const float b2v = (lc<8) ? b2[lc] : 0.f;

  const float* cb = coords + (size_t)((b<<10) + w*256 + lc)*2;
  const float* ab = A2 + (size_t)((b<<10) + w*256 + lc)*64 + lg*8;
  unsigned short* oba = relbf + ((size_t)b<<23) + ((size_t)ia<<10)
                      + ((size_t)(lc&7)<<20) + (unsigned)(w*256 + lg*4);

  for (int st=0; st<16; ++st){
    const float* ap = ab + st*1024;
    float2 cj = *(const float2*)(cb + st*32);
    float4 q0 = *(const float4*)(ap);
    float4 q1 = *(const float4*)(ap+4);
    float4 q2 = *(const float4*)(ap+32);
    float4 q3 = *(const float4*)(ap+36);
    {
      float dx = cia.x-cj.x, dy = cia.y-cj.y;
      float d = sqrtf(fmaf(dx,dx,dy*dy));
      float gg[16];
      g4(d, aA, wA, q0, gg);
      g4(d, aB, wB, q1, gg+4);
      g4(d, aC, wC, q2, gg+8);
      g4(d, aD, wD, q3, gg+12);
      union { unsigned int u[4]; s16x8 v; } p0, p1;
      p0.u[0]=packtr(gg[0],gg[1]);  p0.u[1]=packtr(gg[2],gg[3]);
      p0.u[2]=packtr(gg[4],gg[5]);  p0.u[3]=packtr(gg[6],gg[7]);
      p1.u[0]=packtr(gg[8],gg[9]);  p1.u[1]=packtr(gg[10],gg[11]);
      p1.u[2]=packtr(gg[12],gg[13]);p1.u[3]=packtr(gg[14],gg[15]);
      f32x4 z; z[0]=0.f; z[1]=0.f; z[2]=0.f; z[3]=0.f;
      z = mfma16(p0.v, bf0, z);
      z = mfma16(p1.v, bf1, z);
      if (lc < 8){
        unsigned short* op = oba + st*16;
        *(unsigned int*)op     = pack_bf16(z[0]+b2v, z[1]+b2v);
        *(unsigned int*)(op+2) = pack_bf16(z[2]+b2v, z[3]+b2v);
      }
    }
    {
      float dx = cib.x-cj.x, dy = cib.y-cj.y;
      float d = sqrtf(fmaf(dx,dx,dy*dy));
      float gg[16];
      g4(d, bA, wA, q0, gg);
      g4(d, bB, wB, q1, gg+4);
      g4(d, bC, wC, q2, gg+8);
      g4(d, bD, wD, q3, gg+12);
      union { unsigned int u[4]; s16x8 v; } p0, p1;
      p0.u[0]=packtr(gg[0],gg[1]);  p0.u[1]=packtr(gg[2],gg[3]);
      p0.u[2]=packtr(gg[4],gg[5]);  p0.u[3]=packtr(gg[6],gg[7]);
      p1.u[0]=packtr(gg[8],gg[9]);  p1.u[1]=packtr(gg[10],gg[11]);
      p1.u[2]=packtr(gg[12],gg[13]);p1.u[3]=packtr(gg[14],gg[15]);
      f32x4 z; z[0]=0.f; z[1]=0.f; z[2]=0.f; z[3]=0.f;
      z = mfma16(p0.v, bf0, z);
      z = mfma16(p1.v, bf1, z);
      if (lc < 8){
        unsigned short* op = oba + 1024 + st*16;
        *(unsigned int*)op     = pack_bf16(z[0]+b2v, z[1]+b2v);
        *(unsigned int*)(op+2) = pack_bf16(z[2]+b2v, z[3]+b2v);
      }
    }
  }
}

// ------------- attn v2: swapped-operand MFMA flash, per-lane softmax state ---
// Block = (bh, 16-row i-tile); grid 1024. 4 waves, wave w owns j in [w*256,+256)
// as 16 tiles of 16 j, fully independent (no barrier in loop). Lane l: i = i0+(l&15).
// S^T = mfma(K, Q): lane holds S^T[j=jt+lg*4+r][i]. P^T C-frag == PV B-frag (K=16).
__global__ __launch_bounds__(256) void attn_mfma2(
    const unsigned short* __restrict__ q, const unsigned short* __restrict__ kk,
    const unsigned short* __restrict__ vv, const unsigned short* __restrict__ relbf,
    unsigned short* __restrict__ out){
  int bh = blockIdx.x >> 6;
  int i0 = (blockIdx.x & 63) * 16;
  int tid = threadIdx.x;
  int w = tid>>6, l = tid&63, lc = l&15, lg = l>>4;

  __shared__ __align__(16) float accL[4][2][16][17];
  __shared__ float mL[4][16];
  __shared__ float lL[4][16];

  const unsigned short* qb = q + ((size_t)(bh<<10) + i0)*32;
  const unsigned short* kb = kk + ((size_t)bh<<15);
  const unsigned short* vb = vv + ((size_t)bh<<15);
  const unsigned short* relrow = relbf + ((size_t)bh<<20) + ((size_t)(i0+lc)<<10);

  // Q B-frag: n=lc -> i, k=lg*8+e -> d (scale pre-folded into Wqkv)
  s16x8 qf = *(const s16x8*)(qb + (size_t)lc*32 + lg*8);

  float m = -1e30f, lsum = 0.f;
  f32x4 acc0, acc1;
  acc0[0]=0.f; acc0[1]=0.f; acc0[2]=0.f; acc0[3]=0.f;
  acc1 = acc0;

  for (int t=0; t<16; ++t){
    const int jt = w*256 + t*16;
    // K A-frag: m=lc -> j, k=lg*8+e -> d
    s16x8 kf = *(const s16x8*)(kb + (size_t)(jt+lc)*32 + lg*8);
    f32x4 z; z[0]=0.f; z[1]=0.f; z[2]=0.f; z[3]=0.f;
    f32x4 s = mfma16(kf, qf, z);     // S^T[j=jt+lg*4+r][i=i0+lc]
    ushort4 rl = *(const ushort4*)(relrow + jt + lg*4);
    s[0] += bf2f(rl.x); s[1] += bf2f(rl.y);
    s[2] += bf2f(rl.z); s[3] += bf2f(rl.w);
    // wave-wide row max for i=lc (across lg groups)
    float mx = fmaxf(fmaxf(s[0],s[1]), fmaxf(s[2],s[3]));
    mx = fmaxf(mx, __shfl_xor(mx,16));
    mx = fmaxf(mx, __shfl_xor(mx,32));
    float mn = fmaxf(m, mx);
    float scale = __expf(m - mn);
    m = mn;
    float p0 = __expf(s[0]-mn), p1 = __expf(s[1]-mn);
    float p2 = __expf(s[2]-mn), p3 = __expf(s[3]-mn);
    lsum = lsum*scale + (p0+p1+p2+p3);
    acc0[0]*=scale; acc0[1]*=scale; acc0[2]*=scale; acc0[3]*=scale;
    acc1[0]*=scale; acc1[1]*=scale; acc1[2]*=scale; acc1[3]*=scale;
#if __has_builtin(__builtin_amdgcn_mfma_f32_16x16x16bf16_1k)
    // P^T C-frag is directly the PV B-frag (k=lg*4+e == j rows)
    union { unsigned int u[2]; s16x4 v; } pu;
    pu.u[0] = packtr(p0,p1); pu.u[1] = packtr(p2,p3);
    // V^T A-frags: m=lc -> d (and 16+lc), k=lg*4+e -> j
    const unsigned short* vp = vb + (size_t)(jt + lg*4)*32 + lc;
    s16x4 vf0, vf1;
    vf0[0]=(short)vp[0];  vf0[1]=(short)vp[32];  vf0[2]=(short)vp[64];  vf0[3]=(short)vp[96];
    vf1[0]=(short)vp[16]; vf1[1]=(short)vp[48];  vf1[2]=(short)vp[80];  vf1[3]=(short)vp[112];
    acc0 = __builtin_amdgcn_mfma_f32_16x16x16bf16_1k(vf0, pu.v, acc0, 0,0,0);
    acc1 = __builtin_amdgcn_mfma_f32_16x16x16bf16_1k(vf1, pu.v, acc1, 0,0,0);
#else
    // fallback: K=32 mfma with shuffle-built B-frag (upper 16 k zero)
    unsigned int dw0 = packtr(p0,p1), dw1 = packtr(p2,p3);
    int src0 = lc + (((lg*2)&3)<<4);
    int src1 = lc + (((lg*2+1)&3)<<4);
    unsigned int u0 = __shfl(dw0, src0), u1 = __shfl(dw1, src0);
    unsigned int u2 = __shfl(dw0, src1), u3 = __shfl(dw1, src1);
    if (lg >= 2){ u0=0; u1=0; u2=0; u3=0; }
    union { unsigned int u[4]; s16x8 v; } pb;
    pb.u[0]=u0; pb.u[1]=u1; pb.u[2]=u2; pb.u[3]=u3;
    s16x8 vf0, vf1;
    #pragma unroll
    for (int e=0;e<8;++e){
      int j = (jt + lg*8 + e) & 1023;
      vf0[e] = (short)vb[(size_t)j*32 + lc];
      vf1[e] = (short)vb[(size_t)j*32 + 16 + lc];
    }
    acc0 = mfma16(vf0, pb.v, acc0);
    acc1 = mfma16(vf1, pb.v, acc1);
#endif
  }
  // cross-lg sum of l (m already lg-uniform)
  lsum += __shfl_xor(lsum, 16);
  lsum += __shfl_xor(lsum, 32);
  if (lg == 0){ mL[w][lc] = m; lL[w][lc] = lsum; }
  #pragma unroll
  for (int r=0;r<4;++r){
    accL[w][0][lg*4+r][lc] = acc0[r];
    accL[w][1][lg*4+r][lc] = acc1[r];
  }
  __syncthreads();
  // flash-combine the 4 waves' partials
  int ii = tid & 15, dd = tid >> 4;
  float m0 = mL[0][ii], m1 = mL[1][ii], m2 = mL[2][ii], m3 = mL[3][ii];
  float ms = fmaxf(fmaxf(m0,m1), fmaxf(m2,m3));
  float e0 = __expf(m0-ms), e1 = __expf(m1-ms), e2 = __expf(m2-ms), e3 = __expf(m3-ms);
  float lt = lL[0][ii]*e0 + lL[1][ii]*e1 + lL[2][ii]*e2 + lL[3][ii]*e3;
  float a0 = accL[0][0][dd][ii]*e0 + accL[1][0][dd][ii]*e1
           + accL[2][0][dd][ii]*e2 + accL[3][0][dd][ii]*e3;
  float a1 = accL[0][1][dd][ii]*e0 + accL[1][1][dd][ii]*e1
           + accL[2][1][dd][ii]*e2 + accL[3][1][dd][ii]*e3;
  float inv = 1.0f/lt;
  int b = bh>>3, hh = bh&7;
  size_t ob2 = ((size_t)((b<<10)+i0+ii))*256 + hh*32;
  out[ob2 + dd]      = f2bf(a0*inv);
  out[ob2 + 16 + dd] = f2bf(a1*inv);
}

// ------------- MFMA GEMM: C[M,NC] = A[M,K] @ W[K,NC], A bf16, WT bf16(NC,K) --
template<int K, int NC, int EPI, int BM, int BNt>
__global__ __launch_bounds__(256) void gemm_mfma(
    const unsigned short* __restrict__ Aa, const unsigned short* __restrict__ WT,
    const float* __restrict__ bias, const float* __restrict__ resid,
    void* __restrict__ outv){
  constexpr int WMm = BM/2, WNn = BNt/2;
  constexpr int FM = WMm/16, FN = WNn/16;
  constexpr int LP = 40;
  __shared__ __align__(16) unsigned short As[BM*LP];
  __shared__ __align__(16) unsigned short Bs[BNt*LP];
  const int tid = threadIdx.x;
  const int w = tid>>6, l = tid&63, lc = l&15, lg = l>>4;
  const int wm = w&1, wn = w>>1;
  const int n0 = blockIdx.x*BNt, m0 = blockIdx.y*BM;
  f32x4 acc[FM][FN];
  #pragma unroll
  for (int a=0;a<FM;++a)
    #pragma unroll
    for (int c=0;c<FN;++c){ acc[a][c][0]=0.f; acc[a][c][1]=0.f; acc[a][c][2]=0.f; acc[a][c][3]=0.f; }

  for (int k0=0; k0<K; k0+=32){
    __syncthreads();
    if constexpr (BM==64){
      int row = tid>>2, cg = tid&3;
      *(s16x8*)&As[row*LP+cg*8] = *(const s16x8*)&Aa[(size_t)(m0+row)*K + k0 + cg*8];
    } else {
      int row = tid>>3, cg = tid&7;
      *(ushort4*)&As[row*LP+cg*4] = *(const ushort4*)&Aa[(size_t)(m0+row)*K + k0 + cg*4];
    }
    if constexpr (BNt==64){
      int row = tid>>2, cg = tid&3;
      *(s16x8*)&Bs[row*LP+cg*8] = *(const s16x8*)&WT[(size_t)(n0+row)*K + k0 + cg*8];
    } else {
      int row = tid>>3, cg = tid&7;
      *(ushort4*)&Bs[row*LP+cg*4] = *(const ushort4*)&WT[(size_t)(n0+row)*K + k0 + cg*4];
    }
    __syncthreads();
    s16x8 af[FM], bv[FN];
    #pragma unroll
    for (int a=0;a<FM;++a) af[a] = *(const s16x8*)&As[(wm*WMm + a*16 + lc)*LP + lg*8];
    #pragma unroll
    for (int c=0;c<FN;++c) bv[c] = *(const s16x8*)&Bs[(wn*WNn + c*16 + lc)*LP + lg*8];
    #pragma unroll
    for (int a=0;a<FM;++a)
      #pragma unroll
      for (int c=0;c<FN;++c) acc[a][c] = mfma16(af[a], bv[c], acc[a][c]);
  }
  #pragma unroll
  for (int a=0;a<FM;++a){
    #pragma unroll
    for (int c=0;c<FN;++c){
      int n = n0 + wn*WNn + c*16 + lc;
      float bvv = (EPI!=0) ? bias[n] : 0.f;
      #pragma unroll
      for (int r=0;r<4;++r){
        int m = m0 + wm*WMm + a*16 + lg*4 + r;
        float vv = acc[a][c][r];
        if constexpr (EPI==0){
          ((unsigned short*)outv)[(size_t)m*NC + n] = f2bf(vv);
        } else if constexpr (EPI==1){
          ((float*)outv)[(size_t)m*NC + n] = vv + bvv + resid[(size_t)m*NC + n];
        } else {
          ((unsigned short*)outv)[(size_t)m*NC + n] = f2bf(gelu_f(vv + bvv));
        }
      }
    }
  }
}

extern "C" void kernel_launch(void* const* d_in, const int* in_sizes, int n_in,
                              void* d_out, int out_size, void* d_ws, size_t ws_size,
                              hipStream_t stream){
  const float* x_in  = (const float*)d_in[0];
  const float* coords= (const float*)d_in[1];
  const float* vel   = (const float*)d_in[2];
  const float* ln1_g = (const float*)d_in[3];
  const float* ln1_b = (const float*)d_in[4];
  const float* Wqkv  = (const float*)d_in[5];
  const float* relW1 = (const float*)d_in[6];
  const float* relb1 = (const float*)d_in[7];
  const float* relW2 = (const float*)d_in[8];
  const float* relb2 = (const float*)d_in[9];
  const float* Wout  = (const float*)d_in[10];
  const float* bout  = (const float*)d_in[11];
  const float* ln2_g = (const float*)d_in[12];
  const float* ln2_b = (const float*)d_in[13];
  const float* Wf1   = (const float*)d_in[14];
  const float* bf1   = (const float*)d_in[15];
  const float* Wf2   = (const float*)d_in[16];
  const float* bf2   = (const float*)d_in[17];

  float* x = (float*)d_out;
  unsigned short* us = (unsigned short*)d_ws;
  unsigned short* hbf   = us;                    // 524288
  unsigned short* qkvbf = hbf   + 524288;        // 1572864
  unsigned short* qbf   = qkvbf + 1572864;       // 524288
  unsigned short* kbf   = qbf   + 524288;        // 524288
  unsigned short* vbf   = kbf   + 524288;        // 524288
  unsigned short* attbf = vbf   + 524288;        // 524288
  unsigned short* midbf = attbf + 524288;        // 2097152
  unsigned short* relbf = midbf + 2097152;       // 16777216
  unsigned short* WqkvT = relbf + 16777216;      // 393216
  unsigned short* WoutT = WqkvT + 393216;        // 131072
  unsigned short* Wf1T  = WoutT + 131072;        // 524288
  unsigned short* Wf2T  = Wf1T  + 524288;        // 524288
  unsigned short* W2Tbf = Wf2T  + 524288;        // 1024
  float* Arel  = (float*)(W2Tbf + 1024);         // 131072
  float* A2rel = Arel + 131072;                  // 131072
  float* sint  = A2rel + 131072;                 // 16384
  float* cost  = sint + 16384;                   // 16384

  hipMemcpyAsync(x, x_in, sizeof(float)*524288, hipMemcpyDeviceToDevice, stream);
  rope_table<<<64,256,0,stream>>>(sint,cost);
  wt_convert<<<dim3(24,8,2),256,0,stream>>>(Wqkv, WqkvT, 256, 768, 256, SCALEV);
  wt_convert<<<dim3(8,8,2),256,0,stream>>>(Wout, WoutT, 256, 256, 0, 1.0f);
  wt_convert<<<dim3(32,8,2),256,0,stream>>>(Wf1, Wf1T, 256, 1024, 0, 1.0f);
  wt_convert<<<dim3(8,32,2),256,0,stream>>>(Wf2, Wf2T, 1024, 256, 0, 1.0f);

  for (int l=0;l<2;++l){
    ln_kernel<<<2048,256,0,stream>>>(x, ln1_g+l*256, ln1_b+l*256, hbf);
    gemm_mfma<256,768,0,64,64><<<dim3(12,32),256,0,stream>>>(
        hbf, WqkvT + (size_t)l*196608, nullptr, nullptr, qkvbf);
    rope_apply_bf<<<2048,256,0,stream>>>(qkvbf, sint, cost, qbf, kbf, vbf);
    rel_pre<<<513,256,0,stream>>>(coords, vel, relW1+l*320, relb1+l*64,
                                  relW2+l*512, Arel, A2rel, W2Tbf);
    rel_fused6<<<1024,256,0,stream>>>(coords, Arel, A2rel, relW1+l*320,
                                      W2Tbf, relb2+l*8, relbf);
    attn_mfma2<<<1024,256,0,stream>>>(qbf, kbf, vbf, relbf, attbf);
    gemm_mfma<256,256,1,32,32><<<dim3(8,64),256,0,stream>>>(
        attbf, WoutT + (size_t)l*65536, bout+l*256, x, x);
    ln_kernel<<<2048,256,0,stream>>>(x, ln2_g+l*256, ln2_b+l*256, hbf);
    gemm_mfma<256,1024,2,64,64><<<dim3(16,32),256,0,stream>>>(
        hbf, Wf1T + (size_t)l*262144, bf1+l*1024, nullptr, midbf);
    gemm_mfma<1024,256,1,32,32><<<dim3(8,64),256,0,stream>>>(
        midbf, Wf2T + (size_t)l*262144, bf2+l*256, x, x);
  }
}

// Round 13
// 206.327 us; speedup vs baseline: 1.6235x; 1.0846x over previous
//
#include <hip/hip_runtime.h>
#include <math.h>

#define BN_ 2
#define NN 1024
#define DDIM 256
#define HH 8
#define HDIM 32
#define FFD 1024
#define EPSV 1e-5f
#define SCALEV 0.17677669529663687f

typedef __attribute__((ext_vector_type(8))) short s16x8;
typedef __attribute__((ext_vector_type(4))) short s16x4;
typedef __attribute__((ext_vector_type(4))) float f32x4;
typedef __attribute__((ext_vector_type(2))) _Float16 h2;
typedef __attribute__((ext_vector_type(8))) _Float16 f16x8;

__device__ __forceinline__ float gelu_f(float x){
  return 0.5f*x*(1.0f+erff(x*0.70710678118654752f));
}
__device__ __forceinline__ unsigned int pack_bf16(float lo, float hi){
  unsigned int ul = __float_as_uint(lo), uh = __float_as_uint(hi);
  ul += 0x7fff + ((ul>>16)&1);
  uh += 0x7fff + ((uh>>16)&1);
  return (ul>>16) | (uh & 0xffff0000u);
}
__device__ __forceinline__ unsigned short f2bf(float x){
  unsigned int u = __float_as_uint(x);
  u += 0x7fff + ((u>>16)&1);
  return (unsigned short)(u>>16);
}
__device__ __forceinline__ float bf2f(unsigned short u){
  return __uint_as_float(((unsigned int)u)<<16);
}
__device__ __forceinline__ unsigned int packtr(float lo, float hi){
  return __builtin_amdgcn_perm(__float_as_uint(hi), __float_as_uint(lo), 0x07060302u);
}
__device__ __forceinline__ f32x4 mfma16(s16x8 a, s16x8 b, f32x4 c){
  return __builtin_amdgcn_mfma_f32_16x16x32_bf16(a,b,c,0,0,0);
}
__device__ __forceinline__ f32x4 mfma16h(f16x8 a, f16x8 b, f32x4 c){
  return __builtin_amdgcn_mfma_f32_16x16x32_f16(a,b,c,0,0,0);
}

// ---------------- LayerNorm: f32 in, bf16 out --------------------------------
__global__ __launch_bounds__(256) void ln_kernel(const float* __restrict__ x,
    const float* __restrict__ g, const float* __restrict__ b,
    unsigned short* __restrict__ out){
  int row = blockIdx.x, tid = threadIdx.x;
  float val = x[(size_t)row*DDIM + tid];
  float s = val;
  #pragma unroll
  for (int o=32;o;o>>=1) s += __shfl_xor(s,o);
  __shared__ float sb[4], sb2[4];
  if ((tid&63)==0) sb[tid>>6]=s;
  __syncthreads();
  float mean = (sb[0]+sb[1]+sb[2]+sb[3]) * (1.0f/DDIM);
  float d = val-mean;
  float vs = d*d;
  #pragma unroll
  for (int o=32;o;o>>=1) vs += __shfl_xor(vs,o);
  if ((tid&63)==0) sb2[tid>>6]=vs;
  __syncthreads();
  float var = (sb2[0]+sb2[1]+sb2[2]+sb2[3]) * (1.0f/DDIM);
  out[(size_t)row*DDIM + tid] = f2bf(d*rsqrtf(var+EPSV)*g[tid]+b[tid]);
}

// ---------------- RoPE tables -------------------------------------------------
__global__ __launch_bounds__(256) void rope_table(float* __restrict__ sint, float* __restrict__ cost){
  int idx = blockIdx.x*256+threadIdx.x;   // 16384
  int i = idx >> 4, d = idx & 15;
  float freq = (float)i * powf(10000.0f, -(float)d/16.0f);
  sint[idx]=sinf(freq); cost[idx]=cosf(freq);
}

// ---------------- weight convert+transpose f32(K,NC) -> bf16 WT(NC,K) --------
__global__ __launch_bounds__(256) void wt_convert(const float* __restrict__ in,
    unsigned short* __restrict__ out, int K, int NC, int scaleCols, float scaleVal){
  __shared__ float tile[32][33];
  int tn0 = blockIdx.x*32;
  int tk0 = blockIdx.y*32;
  size_t loff = (size_t)blockIdx.z * K * NC;
  int t = threadIdx.x;
  int col = t & 31, rr = t >> 5;
  #pragma unroll
  for (int i=0;i<4;++i){
    int row = rr + i*8;
    tile[row][col] = in[loff + (size_t)(tk0+row)*NC + tn0+col];
  }
  __syncthreads();
  #pragma unroll
  for (int i=0;i<4;++i){
    int row = rr + i*8;
    int n = tn0 + row;
    float s = (n < scaleCols) ? scaleVal : 1.0f;
    out[loff + (size_t)n*K + tk0 + col] = f2bf(tile[col][row]*s);
  }
}

// ------------- split qkv + rope (bf16 in/out) --------------------------------
__global__ __launch_bounds__(256) void rope_apply_bf(const unsigned short* __restrict__ qkv,
    const float* __restrict__ sint, const float* __restrict__ cost,
    unsigned short* __restrict__ q, unsigned short* __restrict__ k,
    unsigned short* __restrict__ v){
  int row = blockIdx.x;                 // b*1024 + i
  int b = row>>10, i = row&1023;
  int tid = threadIdx.x; int h = tid>>5, d = tid&31;
  const unsigned short* base = qkv + (size_t)row*768;
  size_t oidx = (((size_t)((b<<3)+h)<<10) + i)*32 + d;
  v[oidx] = base[512 + h*32 + d];
  int dd = (d<16) ? d : d-16;
  float s = sint[i*16+dd], c = cost[i*16+dd];
  float q1 = bf2f(base[h*32+dd]), q2 = bf2f(base[h*32+dd+16]);
  q[oidx] = f2bf((d<16) ? (q1*c - q2*s) : (q2*c + q1*s));
  float k1 = bf2f(base[256+h*32+dd]), k2 = bf2f(base[256+h*32+dd+16]);
  k[oidx] = f2bf((d<16) ? (k1*c - k2*s) : (k2*c + k1*s));
}

// ------------- rel precompute: per-node separable parts (fp16) + W2T (f16) ---
// blocks 0..511: A_h[node][64] (=b1+bv), A2_h[node][64] (=bv), both half.
// block 512: W2T_h[16][64] f16 (n<8 valid) + Wd_h[64] half.
__global__ __launch_bounds__(256) void rel_pre(const float* __restrict__ coords,
    const float* __restrict__ vel, const float* __restrict__ W1,
    const float* __restrict__ b1, const float* __restrict__ W2,
    _Float16* __restrict__ A, _Float16* __restrict__ A2,
    _Float16* __restrict__ W2T, _Float16* __restrict__ Wd){
  if (blockIdx.x == 512){
    int t = threadIdx.x;
    #pragma unroll
    for (int e=0;e<4;++e){
      int idx = t*4+e;              // n*64 + k
      int n = idx>>6, kk = idx&63;
      W2T[idx] = (n<8) ? (_Float16)W2[kk*8+n] : (_Float16)0.f;
    }
    if (t < 64) Wd[t] = (_Float16)W1[128+t];
    return;
  }
  int gid = blockIdx.x*256 + threadIdx.x;  // 2048*64
  int node = gid >> 6, r = gid & 63;
  float c0 = coords[node*2], c1 = coords[node*2+1];
  float v0 = vel[node*2],    v1 = vel[node*2+1];
  float bv = c0*W1[r] + c1*W1[64+r] + v0*W1[192+r] + v1*W1[256+r];
  A[gid] = (_Float16)(b1[r] + bv);
  A2[gid] = (_Float16)bv;
}

// ------------- rel fused v7: packed-f16 gelu + f16 MFMA, 2 i's/block ---------
// Block = (b, i-pair); 4 waves; wave w covers j in [w*256,+256) as 16 subtiles
// of 16 j. Lane l: j = j0+(l&15), r in {lg*8..+7, 32+lg*8..+7}. No LDS/barriers.
__global__ __launch_bounds__(256, 4) void rel_fused7(const float* __restrict__ coords,
    const _Float16* __restrict__ A, const _Float16* __restrict__ A2,
    const _Float16* __restrict__ W2T, const _Float16* __restrict__ Wd,
    const float* __restrict__ b2, unsigned short* __restrict__ relbf){
  const int tid = threadIdx.x;
  const int bid = blockIdx.x;            // 1024
  const int b = bid >> 9;
  const int ia = (bid & 511) * 2;        // rows ia, ia+1
  const int w = tid>>6, l = tid&63, lc = l&15, lg = l>>4;
  const int nodea = (b<<10) + ia;
  float2 cia = *(const float2*)(coords + (size_t)nodea*2);
  float2 cib = *(const float2*)(coords + (size_t)nodea*2 + 2);

  // per-lane r-slice invariants (h2 packed)
  union u4h { uint4 u; h2 h[4]; };
  u4h aA, aB, bA, bB, wA, wB;
  aA.u = *(const uint4*)(A + (size_t)nodea*64 + lg*8);
  aB.u = *(const uint4*)(A + (size_t)nodea*64 + 32 + lg*8);
  bA.u = *(const uint4*)(A + (size_t)(nodea+1)*64 + lg*8);
  bB.u = *(const uint4*)(A + (size_t)(nodea+1)*64 + 32 + lg*8);
  wA.u = *(const uint4*)(Wd + lg*8);
  wB.u = *(const uint4*)(Wd + 32 + lg*8);

  const f16x8 bf0 = *(const f16x8*)&W2T[lc*64 + lg*8];
  const f16x8 bf1 = *(const f16x8*)&W2T[lc*64 + 32 + lg*8];
  const float b2v = (lc<8) ? b2[lc] : 0.f;

  const h2 c2 = {(_Float16)0.0099735570f, (_Float16)0.0099735570f};
  const h2 c1 = {(_Float16)-0.0664904395f, (_Float16)-0.0664904395f};
  const h2 c0 = {(_Float16)0.3989422804f, (_Float16)0.3989422804f};
  const h2 ch = {(_Float16)0.5f, (_Float16)0.5f};

  const float* cb = coords + (size_t)((b<<10) + w*256 + lc)*2;
  const _Float16* ab = A2 + (size_t)((b<<10) + w*256 + lc)*64 + lg*8;
  unsigned short* oba = relbf + ((size_t)b<<23) + ((size_t)ia<<10)
                      + ((size_t)(lc&7)<<20) + (unsigned)(w*256 + lg*4);

  for (int st=0; st<16; ++st){
    u4h t0, t1;
    t0.u = *(const uint4*)(ab + st*1024);
    t1.u = *(const uint4*)(ab + st*1024 + 32);
    float2 cj = *(const float2*)(cb + st*32);
    // ---- i_a ----
    {
      float dx = cia.x-cj.x, dy = cia.y-cj.y;
      _Float16 dh = (_Float16)sqrtf(fmaf(dx,dx,dy*dy));
      h2 d2 = {dh, dh};
      union { h2 h[4]; f16x8 v; } g0, g1;
      #pragma unroll
      for (int e=0;e<4;++e){
        h2 t = (aA.h[e] - t0.h[e]) + d2*wA.h[e];
        h2 u = t*t;
        h2 p = u*c2 + c1;
        p = u*p + c0;
        g0.h[e] = u*p + ch*t;
        h2 s = (aB.h[e] - t1.h[e]) + d2*wB.h[e];
        h2 v = s*s;
        h2 q = v*c2 + c1;
        q = v*q + c0;
        g1.h[e] = v*q + ch*s;
      }
      f32x4 z; z[0]=0.f; z[1]=0.f; z[2]=0.f; z[3]=0.f;
      z = mfma16h(g0.v, bf0, z);
      z = mfma16h(g1.v, bf1, z);
      if (lc < 8){
        unsigned short* op = oba + st*16;
        *(unsigned int*)op     = pack_bf16(z[0]+b2v, z[1]+b2v);
        *(unsigned int*)(op+2) = pack_bf16(z[2]+b2v, z[3]+b2v);
      }
    }
    // ---- i_b (same t0/t1/cj loads) ----
    {
      float dx = cib.x-cj.x, dy = cib.y-cj.y;
      _Float16 dh = (_Float16)sqrtf(fmaf(dx,dx,dy*dy));
      h2 d2 = {dh, dh};
      union { h2 h[4]; f16x8 v; } g0, g1;
      #pragma unroll
      for (int e=0;e<4;++e){
        h2 t = (bA.h[e] - t0.h[e]) + d2*wA.h[e];
        h2 u = t*t;
        h2 p = u*c2 + c1;
        p = u*p + c0;
        g0.h[e] = u*p + ch*t;
        h2 s = (bB.h[e] - t1.h[e]) + d2*wB.h[e];
        h2 v = s*s;
        h2 q = v*c2 + c1;
        q = v*q + c0;
        g1.h[e] = v*q + ch*s;
      }
      f32x4 z; z[0]=0.f; z[1]=0.f; z[2]=0.f; z[3]=0.f;
      z = mfma16h(g0.v, bf0, z);
      z = mfma16h(g1.v, bf1, z);
      if (lc < 8){
        unsigned short* op = oba + 1024 + st*16;
        *(unsigned int*)op     = pack_bf16(z[0]+b2v, z[1]+b2v);
        *(unsigned int*)(op+2) = pack_bf16(z[2]+b2v, z[3]+b2v);
      }
    }
  }
}

// ------------- attn v2: swapped-operand MFMA flash, per-lane softmax state ---
__global__ __launch_bounds__(256) void attn_mfma2(
    const unsigned short* __restrict__ q, const unsigned short* __restrict__ kk,
    const unsigned short* __restrict__ vv, const unsigned short* __restrict__ relbf,
    unsigned short* __restrict__ out){
  int bh = blockIdx.x >> 6;
  int i0 = (blockIdx.x & 63) * 16;
  int tid = threadIdx.x;
  int w = tid>>6, l = tid&63, lc = l&15, lg = l>>4;

  __shared__ __align__(16) float accL[4][2][16][17];
  __shared__ float mL[4][16];
  __shared__ float lL[4][16];

  const unsigned short* qb = q + ((size_t)(bh<<10) + i0)*32;
  const unsigned short* kb = kk + ((size_t)bh<<15);
  const unsigned short* vb = vv + ((size_t)bh<<15);
  const unsigned short* relrow = relbf + ((size_t)bh<<20) + ((size_t)(i0+lc)<<10);

  s16x8 qf = *(const s16x8*)(qb + (size_t)lc*32 + lg*8);

  float m = -1e30f, lsum = 0.f;
  f32x4 acc0, acc1;
  acc0[0]=0.f; acc0[1]=0.f; acc0[2]=0.f; acc0[3]=0.f;
  acc1 = acc0;

  for (int t=0; t<16; ++t){
    const int jt = w*256 + t*16;
    s16x8 kf = *(const s16x8*)(kb + (size_t)(jt+lc)*32 + lg*8);
    f32x4 z; z[0]=0.f; z[1]=0.f; z[2]=0.f; z[3]=0.f;
    f32x4 s = mfma16(kf, qf, z);     // S^T[j=jt+lg*4+r][i=i0+lc]
    ushort4 rl = *(const ushort4*)(relrow + jt + lg*4);
    s[0] += bf2f(rl.x); s[1] += bf2f(rl.y);
    s[2] += bf2f(rl.z); s[3] += bf2f(rl.w);
    float mx = fmaxf(fmaxf(s[0],s[1]), fmaxf(s[2],s[3]));
    mx = fmaxf(mx, __shfl_xor(mx,16));
    mx = fmaxf(mx, __shfl_xor(mx,32));
    float mn = fmaxf(m, mx);
    float scale = __expf(m - mn);
    m = mn;
    float p0 = __expf(s[0]-mn), p1 = __expf(s[1]-mn);
    float p2 = __expf(s[2]-mn), p3 = __expf(s[3]-mn);
    lsum = lsum*scale + (p0+p1+p2+p3);
    acc0[0]*=scale; acc0[1]*=scale; acc0[2]*=scale; acc0[3]*=scale;
    acc1[0]*=scale; acc1[1]*=scale; acc1[2]*=scale; acc1[3]*=scale;
#if __has_builtin(__builtin_amdgcn_mfma_f32_16x16x16bf16_1k)
    union { unsigned int u[2]; s16x4 v; } pu;
    pu.u[0] = packtr(p0,p1); pu.u[1] = packtr(p2,p3);
    const unsigned short* vp = vb + (size_t)(jt + lg*4)*32 + lc;
    s16x4 vf0, vf1;
    vf0[0]=(short)vp[0];  vf0[1]=(short)vp[32];  vf0[2]=(short)vp[64];  vf0[3]=(short)vp[96];
    vf1[0]=(short)vp[16]; vf1[1]=(short)vp[48];  vf1[2]=(short)vp[80];  vf1[3]=(short)vp[112];
    acc0 = __builtin_amdgcn_mfma_f32_16x16x16bf16_1k(vf0, pu.v, acc0, 0,0,0);
    acc1 = __builtin_amdgcn_mfma_f32_16x16x16bf16_1k(vf1, pu.v, acc1, 0,0,0);
#else
    unsigned int dw0 = packtr(p0,p1), dw1 = packtr(p2,p3);
    int src0 = lc + (((lg*2)&3)<<4);
    int src1 = lc + (((lg*2+1)&3)<<4);
    unsigned int u0 = __shfl(dw0, src0), u1 = __shfl(dw1, src0);
    unsigned int u2 = __shfl(dw0, src1), u3 = __shfl(dw1, src1);
    if (lg >= 2){ u0=0; u1=0; u2=0; u3=0; }
    union { unsigned int u[4]; s16x8 v; } pb;
    pb.u[0]=u0; pb.u[1]=u1; pb.u[2]=u2; pb.u[3]=u3;
    s16x8 vf0, vf1;
    #pragma unroll
    for (int e=0;e<8;++e){
      int j = (jt + lg*8 + e) & 1023;
      vf0[e] = (short)vb[(size_t)j*32 + lc];
      vf1[e] = (short)vb[(size_t)j*32 + 16 + lc];
    }
    acc0 = mfma16(vf0, pb.v, acc0);
    acc1 = mfma16(vf1, pb.v, acc1);
#endif
  }
  lsum += __shfl_xor(lsum, 16);
  lsum += __shfl_xor(lsum, 32);
  if (lg == 0){ mL[w][lc] = m; lL[w][lc] = lsum; }
  #pragma unroll
  for (int r=0;r<4;++r){
    accL[w][0][lg*4+r][lc] = acc0[r];
    accL[w][1][lg*4+r][lc] = acc1[r];
  }
  __syncthreads();
  int ii = tid & 15, dd = tid >> 4;
  float m0 = mL[0][ii], m1 = mL[1][ii], m2 = mL[2][ii], m3 = mL[3][ii];
  float ms = fmaxf(fmaxf(m0,m1), fmaxf(m2,m3));
  float e0 = __expf(m0-ms), e1 = __expf(m1-ms), e2 = __expf(m2-ms), e3 = __expf(m3-ms);
  float lt = lL[0][ii]*e0 + lL[1][ii]*e1 + lL[2][ii]*e2 + lL[3][ii]*e3;
  float a0 = accL[0][0][dd][ii]*e0 + accL[1][0][dd][ii]*e1
           + accL[2][0][dd][ii]*e2 + accL[3][0][dd][ii]*e3;
  float a1 = accL[0][1][dd][ii]*e0 + accL[1][1][dd][ii]*e1
           + accL[2][1][dd][ii]*e2 + accL[3][1][dd][ii]*e3;
  float inv = 1.0f/lt;
  int b = bh>>3, hh = bh&7;
  size_t ob2 = ((size_t)((b<<10)+i0+ii))*256 + hh*32;
  out[ob2 + dd]      = f2bf(a0*inv);
  out[ob2 + 16 + dd] = f2bf(a1*inv);
}

// ------------- MFMA GEMM: C[M,NC] = A[M,K] @ W[K,NC], A bf16, WT bf16(NC,K) --
template<int K, int NC, int EPI, int BM, int BNt>
__global__ __launch_bounds__(256) void gemm_mfma(
    const unsigned short* __restrict__ Aa, const unsigned short* __restrict__ WT,
    const float* __restrict__ bias, const float* __restrict__ resid,
    void* __restrict__ outv){
  constexpr int WMm = BM/2, WNn = BNt/2;
  constexpr int FM = WMm/16, FN = WNn/16;
  constexpr int LP = 40;
  __shared__ __align__(16) unsigned short As[BM*LP];
  __shared__ __align__(16) unsigned short Bs[BNt*LP];
  const int tid = threadIdx.x;
  const int w = tid>>6, l = tid&63, lc = l&15, lg = l>>4;
  const int wm = w&1, wn = w>>1;
  const int n0 = blockIdx.x*BNt, m0 = blockIdx.y*BM;
  f32x4 acc[FM][FN];
  #pragma unroll
  for (int a=0;a<FM;++a)
    #pragma unroll
    for (int c=0;c<FN;++c){ acc[a][c][0]=0.f; acc[a][c][1]=0.f; acc[a][c][2]=0.f; acc[a][c][3]=0.f; }

  for (int k0=0; k0<K; k0+=32){
    __syncthreads();
    if constexpr (BM==64){
      int row = tid>>2, cg = tid&3;
      *(s16x8*)&As[row*LP+cg*8] = *(const s16x8*)&Aa[(size_t)(m0+row)*K + k0 + cg*8];
    } else {
      int row = tid>>3, cg = tid&7;
      *(ushort4*)&As[row*LP+cg*4] = *(const ushort4*)&Aa[(size_t)(m0+row)*K + k0 + cg*4];
    }
    if constexpr (BNt==64){
      int row = tid>>2, cg = tid&3;
      *(s16x8*)&Bs[row*LP+cg*8] = *(const s16x8*)&WT[(size_t)(n0+row)*K + k0 + cg*8];
    } else {
      int row = tid>>3, cg = tid&7;
      *(ushort4*)&Bs[row*LP+cg*4] = *(const ushort4*)&WT[(size_t)(n0+row)*K + k0 + cg*4];
    }
    __syncthreads();
    s16x8 af[FM], bv[FN];
    #pragma unroll
    for (int a=0;a<FM;++a) af[a] = *(const s16x8*)&As[(wm*WMm + a*16 + lc)*LP + lg*8];
    #pragma unroll
    for (int c=0;c<FN;++c) bv[c] = *(const s16x8*)&Bs[(wn*WNn + c*16 + lc)*LP + lg*8];
    #pragma unroll
    for (int a=0;a<FM;++a)
      #pragma unroll
      for (int c=0;c<FN;++c) acc[a][c] = mfma16(af[a], bv[c], acc[a][c]);
  }
  #pragma unroll
  for (int a=0;a<FM;++a){
    #pragma unroll
    for (int c=0;c<FN;++c){
      int n = n0 + wn*WNn + c*16 + lc;
      float bvv = (EPI!=0) ? bias[n] : 0.f;
      #pragma unroll
      for (int r=0;r<4;++r){
        int m = m0 + wm*WMm + a*16 + lg*4 + r;
        float vv = acc[a][c][r];
        if constexpr (EPI==0){
          ((unsigned short*)outv)[(size_t)m*NC + n] = f2bf(vv);
        } else if constexpr (EPI==1){
          ((float*)outv)[(size_t)m*NC + n] = vv + bvv + resid[(size_t)m*NC + n];
        } else {
          ((unsigned short*)outv)[(size_t)m*NC + n] = f2bf(gelu_f(vv + bvv));
        }
      }
    }
  }
}

extern "C" void kernel_launch(void* const* d_in, const int* in_sizes, int n_in,
                              void* d_out, int out_size, void* d_ws, size_t ws_size,
                              hipStream_t stream){
  const float* x_in  = (const float*)d_in[0];
  const float* coords= (const float*)d_in[1];
  const float* vel   = (const float*)d_in[2];
  const float* ln1_g = (const float*)d_in[3];
  const float* ln1_b = (const float*)d_in[4];
  const float* Wqkv  = (const float*)d_in[5];
  const float* relW1 = (const float*)d_in[6];
  const float* relb1 = (const float*)d_in[7];
  const float* relW2 = (const float*)d_in[8];
  const float* relb2 = (const float*)d_in[9];
  const float* Wout  = (const float*)d_in[10];
  const float* bout  = (const float*)d_in[11];
  const float* ln2_g = (const float*)d_in[12];
  const float* ln2_b = (const float*)d_in[13];
  const float* Wf1   = (const float*)d_in[14];
  const float* bf1   = (const float*)d_in[15];
  const float* Wf2   = (const float*)d_in[16];
  const float* bf2   = (const float*)d_in[17];

  float* x = (float*)d_out;
  unsigned short* us = (unsigned short*)d_ws;
  unsigned short* hbf   = us;                    // 524288
  unsigned short* qkvbf = hbf   + 524288;        // 1572864
  unsigned short* qbf   = qkvbf + 1572864;       // 524288
  unsigned short* kbf   = qbf   + 524288;        // 524288
  unsigned short* vbf   = kbf   + 524288;        // 524288
  unsigned short* attbf = vbf   + 524288;        // 524288
  unsigned short* midbf = attbf + 524288;        // 2097152
  unsigned short* relbf = midbf + 2097152;       // 16777216
  unsigned short* WqkvT = relbf + 16777216;      // 393216
  unsigned short* WoutT = WqkvT + 393216;        // 131072
  unsigned short* Wf1T  = WoutT + 131072;        // 524288
  unsigned short* Wf2T  = Wf1T  + 524288;        // 524288
  _Float16* W2Th = (_Float16*)(Wf2T + 524288);   // 1024
  _Float16* Wdh  = W2Th + 1024;                  // 64
  _Float16* Ah   = Wdh + 64;                     // 131072
  _Float16* A2h  = Ah + 131072;                  // 131072
  float* sint  = (float*)(A2h + 131072);         // 16384
  float* cost  = sint + 16384;                   // 16384

  hipMemcpyAsync(x, x_in, sizeof(float)*524288, hipMemcpyDeviceToDevice, stream);
  rope_table<<<64,256,0,stream>>>(sint,cost);
  wt_convert<<<dim3(24,8,2),256,0,stream>>>(Wqkv, WqkvT, 256, 768, 256, SCALEV);
  wt_convert<<<dim3(8,8,2),256,0,stream>>>(Wout, WoutT, 256, 256, 0, 1.0f);
  wt_convert<<<dim3(32,8,2),256,0,stream>>>(Wf1, Wf1T, 256, 1024, 0, 1.0f);
  wt_convert<<<dim3(8,32,2),256,0,stream>>>(Wf2, Wf2T, 1024, 256, 0, 1.0f);

  for (int l=0;l<2;++l){
    ln_kernel<<<2048,256,0,stream>>>(x, ln1_g+l*256, ln1_b+l*256, hbf);
    gemm_mfma<256,768,0,64,64><<<dim3(12,32),256,0,stream>>>(
        hbf, WqkvT + (size_t)l*196608, nullptr, nullptr, qkvbf);
    rope_apply_bf<<<2048,256,0,stream>>>(qkvbf, sint, cost, qbf, kbf, vbf);
    rel_pre<<<513,256,0,stream>>>(coords, vel, relW1+l*320, relb1+l*64,
                                  relW2+l*512, Ah, A2h, W2Th, Wdh);
    rel_fused7<<<1024,256,0,stream>>>(coords, Ah, A2h, W2Th, Wdh,
                                      relb2+l*8, relbf);
    attn_mfma2<<<1024,256,0,stream>>>(qbf, kbf, vbf, relbf, attbf);
    gemm_mfma<256,256,1,32,32><<<dim3(8,64),256,0,stream>>>(
        attbf, WoutT + (size_t)l*65536, bout+l*256, x, x);
    ln_kernel<<<2048,256,0,stream>>>(x, ln2_g+l*256, ln2_b+l*256, hbf);
    gemm_mfma<256,1024,2,64,64><<<dim3(16,32),256,0,stream>>>(
        hbf, Wf1T + (size_t)l*262144, bf1+l*1024, nullptr, midbf);
    gemm_mfma<1024,256,1,32,32><<<dim3(8,64),256,0,stream>>>(
        midbf, Wf2T + (size_t)l*262144, bf2+l*256, x, x);
  }
}